// Round 3
// baseline (22259.311 us; speedup 1.0000x reference)
//
#include <hip/hip_runtime.h>
#include <math.h>

#define NT 1024

__device__ __forceinline__ float sigf(float x)   { return 1.0f / (1.0f + __expf(-x)); }
__device__ __forceinline__ float tanhf_(float x) { return 1.0f - 2.0f / (1.0f + __expf(2.0f * x)); }
__device__ __forceinline__ float dot4(float4 a, float4 b) {
    return a.x * b.x + a.y * b.y + a.z * b.z + a.w * b.w;
}
__device__ __forceinline__ float red16(float v) {
    v += __shfl_xor(v, 1); v += __shfl_xor(v, 2);
    v += __shfl_xor(v, 4); v += __shfl_xor(v, 8);
    return v;
}
__device__ __forceinline__ float red64(float v) {
    v += __shfl_xor(v, 1);  v += __shfl_xor(v, 2);  v += __shfl_xor(v, 4);
    v += __shfl_xor(v, 8);  v += __shfl_xor(v, 16); v += __shfl_xor(v, 32);
    return v;
}

// 4-block group barrier: device-scope atomic counter + spin. Groups are
// independent (no cross-group waits), so forward progress is guaranteed even
// without full co-residency.
__device__ __forceinline__ void gbar(unsigned* ctr, unsigned target) {
    __threadfence();          // release: make this block's global writes visible
    __syncthreads();
    if (threadIdx.x == 0) {
        __hip_atomic_fetch_add(ctr, 1u, __ATOMIC_RELAXED, __HIP_MEMORY_SCOPE_AGENT);
        while (__hip_atomic_load(ctr, __ATOMIC_RELAXED, __HIP_MEMORY_SCOPE_AGENT) < target)
            __builtin_amdgcn_s_sleep(8);
        __threadfence();      // acquire
    }
    __syncthreads();
}

// 256 gate rows (this block's slice), wave-per-row, two 256-float strips.
// Lanes read 1KB contiguous per strip per row (perfect coalescing).
__device__ __forceinline__ void gemv2s(const float* __restrict__ WA, int strideA,
                                       const float* __restrict__ WB, int strideB,
                                       const float4* actA4, const float4* actB4,
                                       const float* bias, float* outg, int co) {
    const int w = threadIdx.x >> 6, lane = threadIdx.x & 63;
    const int g = w >> 2, cb = (w & 3) << 4;
    const int j0 = g * 256 + co * 64 + cb;
    float4 aA = actA4[lane], aB = actB4[lane];
    #pragma unroll 2
    for (int r = 0; r < 16; ++r) {
        int j = j0 + r;
        const float4* wa = (const float4*)(WA + (size_t)j * strideA);
        const float4* wb = (const float4*)(WB + (size_t)j * strideB);
        float s = dot4(wa[lane], aA) + dot4(wb[lane], aB);
        s = red64(s);
        if (lane == 0) { int ridx = (g << 6) + cb + r; outg[ridx] = s + bias[ridx]; }
    }
}

// One block per (batch, channel-slice). blockIdx = b*4 + co.
extern "C" __global__ void __launch_bounds__(NT)
attn_lstm_v3(const float* __restrict__ inp,
             const float* __restrict__ wihe0, const float* __restrict__ wihe1,
             const float* __restrict__ whhe,
             const float* __restrict__ bihe,  const float* __restrict__ bhhe,
             const float* __restrict__ wihd0r, const float* __restrict__ wihd1,
             const float* __restrict__ whhd,
             const float* __restrict__ bihd,  const float* __restrict__ bhhd,
             const float* __restrict__ aw1,   const float* __restrict__ ab1,
             const float* __restrict__ aw2,
             const float* __restrict__ dw1,   const float* __restrict__ db1,
             const float* __restrict__ dw2,
             const float* __restrict__ pw,    const float* __restrict__ pb,
             float* __restrict__ h0_g, float* __restrict__ h1c1_g,
             float* __restrict__ hctd_g, unsigned* __restrict__ barc,
             float* __restrict__ out)
{
    extern __shared__ __align__(16) float sm[];
    float* hexpL  = sm;            // 16384  h_expanded (full local copy)
    float* reg2   = sm + 16384;    // 16384  xeT (enc) | PdL (dec)
    float* xinL   = sm + 32768;    // 64
    float* actP   = sm + 32832;    // 264  [partial(256)|d_t|0,0,0|pad4]
    float* h0L    = sm + 33096;    // 256
    float* hc1f   = sm + 33352;    // 512  [h1|c1]
    float* gsl    = sm + 33864;    // 256  gate slice
    float* hctL   = sm + 34120;    // 256
    float* scoreS = sm + 34376;    // 64
    float* aS     = sm + 34440;    // 64
    float* c0L    = sm + 34504;    // 64   (block-private c0 slice)
    float* decinL = sm + 34568;    // 64
    float* bE0s   = sm + 34632;    // 256
    float* bE1s   = sm + 34888;    // 256
    float* bD0s   = sm + 35144;    // 256
    float* bD1s   = sm + 35400;    // 256 -> total 35656 floats

    const int tid = threadIdx.x;
    const int b   = blockIdx.x >> 2;
    const int co  = blockIdx.x & 3;
    unsigned* ctr = barc + (b << 4);
    unsigned  ph  = 0;

    // ---- init ----
    for (int i = tid; i < 1864; i += NT) sm[32768 + i] = 0.0f;  // xinL..decinL region
    if (tid < 256) {
        int g = tid >> 6, c = tid & 63;
        int j = g * 256 + co * 64 + c;
        bE0s[tid] = bihe[j]        + bhhe[j];
        bE1s[tid] = bihe[1024 + j] + bhhe[1024 + j];
        bD0s[tid] = bihd[j]        + bhhd[j];
        bD1s[tid] = bihd[1024 + j] + bhhd[1024 + j];
    }
    const float* ib = inp + b * (64 * 65);
    float* xeT = reg2;                       // 64 rows x 68 (padded)
    for (int i = tid; i < 4096; i += NT) {
        int t = i & 63, e = i >> 6;
        xeT[e * 68 + t] = ib[t * 65 + 1 + e];
    }
    if (tid < 64) decinL[tid] = ib[tid * 65];
    __syncthreads();

    const int g16 = tid >> 4, q16 = tid & 15;
    const int w   = tid >> 6, lane = tid & 63;

    // ---- encoder attention P (input part + bias) -> regs ----
    float Preg[4], w2r[4];
    #pragma unroll
    for (int jj = 0; jj < 4; ++jj) {
        int j = q16 + 16 * jj;
        w2r[jj] = aw2[j];
        float acc = ab1[j];
        const float4* w4 = (const float4*)(aw1 + j * 576 + 512);
        const float4* x4 = (const float4*)(xeT + g16 * 68);
        #pragma unroll 4
        for (int k = 0; k < 16; ++k) acc += dot4(w4[k], x4[k]);
        Preg[jj] = acc;
    }

    // ================= encoder: 64 steps, 2 group-barriers each =============
    for (int t = 0; t < 64; ++t) {
        // E1: hct[j<64] = [h1;c1] . aw1[j,0:512)   (redundant; 4 rows/wave)
        {
            const float4* h4 = (const float4*)hc1f;
            float4 a0 = h4[lane], a1 = h4[64 + lane];
            #pragma unroll
            for (int i = 0; i < 4; ++i) {
                int j = w * 4 + i;
                const float4* w4 = (const float4*)(aw1 + (size_t)j * 576);
                float s = dot4(w4[lane], a0) + dot4(w4[64 + lane], a1);
                s = red64(s);
                if (lane == 0) hctL[j] = s;
            }
        }
        __syncthreads();
        // E2: score
        {
            float s = 0.f;
            #pragma unroll
            for (int jj = 0; jj < 4; ++jj)
                s += tanhf_(Preg[jj] + hctL[q16 + 16 * jj]) * w2r[jj];
            s = red16(s);
            if (q16 == 0) scoreS[g16] = s;
        }
        __syncthreads();
        // E3: softmax + x_in
        if (tid < 64) {
            float v = scoreS[tid], m = v;
            #pragma unroll
            for (int d = 1; d < 64; d <<= 1) m = fmaxf(m, __shfl_xor(m, d));
            float ex = __expf(v - m), s = ex;
            #pragma unroll
            for (int d = 1; d < 64; d <<= 1) s += __shfl_xor(s, d);
            xinL[tid] = (ex / s) * xeT[tid * 68 + t];
        }
        __syncthreads();
        // E4: layer0 gate slice: wihe0 (64-wide, lanes<16) + whhe_l0 (256-wide)
        {
            const int g = w >> 2, cb = (w & 3) << 4;
            const int j0 = g * 256 + co * 64 + cb;
            const float4* x4 = (const float4*)xinL;
            const float4* h4 = (const float4*)h0L;
            float4 aA = make_float4(0.f, 0.f, 0.f, 0.f);
            if (lane < 16) aA = x4[lane];
            float4 aB = h4[lane];
            #pragma unroll 2
            for (int r = 0; r < 16; ++r) {
                int j = j0 + r;
                const float4* wb = (const float4*)(whhe + (size_t)j * 256);
                float s = dot4(wb[lane], aB);
                if (lane < 16) {
                    const float4* wa = (const float4*)(wihe0 + (size_t)j * 64);
                    s += dot4(wa[lane], aA);
                }
                s = red64(s);
                if (lane == 0) { int ridx = (g << 6) + cb + r; gsl[ridx] = s + bE0s[ridx]; }
            }
        }
        __syncthreads();
        // E5: elementwise l0 (owner slice) -> h0_g
        if (tid < 64) {
            float cn = sigf(gsl[64 + tid]) * c0L[tid] + sigf(gsl[tid]) * tanhf_(gsl[128 + tid]);
            float hn = sigf(gsl[192 + tid]) * tanhf_(cn);
            c0L[tid] = cn;
            h0_g[b * 256 + co * 64 + tid] = hn;
        }
        gbar(ctr, (++ph) * 4);
        if (tid < 256) h0L[tid] = h0_g[b * 256 + tid];
        __syncthreads();
        // E6: layer1 gate slice: wihe1 x h0 + whhe_l1 x h1
        gemv2s(wihe1, 256, whhe + 262144, 256,
               (const float4*)h0L, (const float4*)hc1f, bE1s, gsl, co);
        __syncthreads();
        // E7: elementwise l1 -> h1c1_g
        if (tid < 64) {
            float cp = hc1f[256 + co * 64 + tid];
            float cn = sigf(gsl[64 + tid]) * cp + sigf(gsl[tid]) * tanhf_(gsl[128 + tid]);
            float hn = sigf(gsl[192 + tid]) * tanhf_(cn);
            h1c1_g[b * 512 + co * 64 + tid]       = hn;
            h1c1_g[b * 512 + 256 + co * 64 + tid] = cn;
        }
        gbar(ctr, (++ph) * 4);
        if (tid < 512) {
            float v = h1c1_g[b * 512 + tid];
            hc1f[tid] = v;
            if (tid < 256) hexpL[t * 256 + tid] = v;
        }
        __syncthreads();
    }

    // ---- transition: zero recurrent state; Pd -> LDS (overwrites xeT) ----
    for (int i = tid; i < 512; i += NT) hc1f[i] = 0.0f;
    if (tid < 256) h0L[tid] = 0.0f;
    if (tid < 64)  c0L[tid] = 0.0f;
    __syncthreads();
    float* PdL = reg2;   // [t'(64)][j(256)]
    {
        const int tq = tid & 7, jj8 = tid >> 3;   // 8-way K split, 128 j per pass
        #pragma unroll
        for (int p = 0; p < 2; ++p) {
            int j = p * 128 + jj8;
            const float4* w4 = (const float4*)(dw1 + (size_t)j * 768 + 512 + tq * 32);
            float4 wreg[8];
            #pragma unroll
            for (int i = 0; i < 8; ++i) wreg[i] = w4[i];
            float bj = db1[j];
            for (int tp = 0; tp < 64; ++tp) {
                const float4* hx = (const float4*)(hexpL + tp * 256) + tq * 8;
                float s = 0.f;
                #pragma unroll
                for (int i = 0; i < 8; ++i) s += dot4(wreg[i], hx[i]);
                s += __shfl_xor(s, 1); s += __shfl_xor(s, 2); s += __shfl_xor(s, 4);
                if (tq == 0) PdL[tp * 256 + j] = s + bj;
            }
        }
    }
    float w2dr[16];
    #pragma unroll
    for (int jj = 0; jj < 16; ++jj) w2dr[jj] = dw2[q16 + 16 * jj];
    __syncthreads();

    // ================= decoder: 64 steps, 3 group-barriers each =============
    const int j4 = tid >> 2, q4 = tid & 3;
    for (int t = 0; t < 64; ++t) {
        // D0: hct slice (64 rows of dw1[:,0:512)) -> gsl -> global
        {
            const float4* h4 = (const float4*)hc1f;
            float4 a0 = h4[lane], a1 = h4[64 + lane];
            #pragma unroll
            for (int i = 0; i < 4; ++i) {
                int jl = w * 4 + i;
                const float4* w4 = (const float4*)(dw1 + (size_t)(co * 64 + jl) * 768);
                float s = dot4(w4[lane], a0) + dot4(w4[64 + lane], a1);
                s = red64(s);
                if (lane == 0) gsl[jl] = s;
            }
        }
        __syncthreads();
        if (tid < 64) hctd_g[b * 256 + co * 64 + tid] = gsl[tid];
        gbar(ctr, (++ph) * 4);
        if (tid < 256) hctL[tid] = hctd_g[b * 256 + tid];
        __syncthreads();
        // D2: score
        {
            float s = 0.f;
            #pragma unroll
            for (int jj = 0; jj < 16; ++jj)
                s += tanhf_(PdL[g16 * 256 + q16 + 16 * jj] + hctL[q16 + 16 * jj]) * w2dr[jj];
            s = red16(s);
            if (q16 == 0) scoreS[g16] = s;
        }
        __syncthreads();
        // D3: softmax -> aS; stage d_t
        if (tid < 64) {
            float v = scoreS[tid], m = v;
            #pragma unroll
            for (int d = 1; d < 64; d <<= 1) m = fmaxf(m, __shfl_xor(m, d));
            float ex = __expf(v - m), s = ex;
            #pragma unroll
            for (int d = 1; d < 64; d <<= 1) s += __shfl_xor(s, d);
            aS[tid] = ex / s;
            if (tid == 0) actP[256] = decinL[t];
        }
        __syncthreads();
        // D4: partial[c] = sum_t' hexp[t'][c] * a[t']   (redundant)
        {
            float acc = 0.f;
            #pragma unroll 4
            for (int i = 0; i < 16; ++i) {
                int tt = q4 + 4 * i;
                acc += hexpL[tt * 256 + j4] * aS[tt];
            }
            acc += __shfl_xor(acc, 1);
            acc += __shfl_xor(acc, 2);
            if (q4 == 0) actP[j4] = acc;
        }
        __syncthreads();
        // D5: layer0 gate slice: wihd0r (260-wide: partial+d_t) + whhd_l0 x h0
        {
            const int g = w >> 2, cb = (w & 3) << 4;
            const int j0 = g * 256 + co * 64 + cb;
            const float4* p4 = (const float4*)actP;
            const float4* h4 = (const float4*)h0L;
            float4 aA = p4[lane], aB = h4[lane];
            float4 aC = p4[64];                    // [d_t,0,0,0]
            #pragma unroll 2
            for (int r = 0; r < 16; ++r) {
                int j = j0 + r;
                const float4* wa = (const float4*)(wihd0r + (size_t)j * 260);
                const float4* wb = (const float4*)(whhd + (size_t)j * 256);
                float s = dot4(wa[lane], aA) + dot4(wb[lane], aB);
                if (lane == 0) s += dot4(wa[64], aC);
                s = red64(s);
                if (lane == 0) { int ridx = (g << 6) + cb + r; gsl[ridx] = s + bD0s[ridx]; }
            }
        }
        __syncthreads();
        // D6: elementwise l0 -> h0_g
        if (tid < 64) {
            float cn = sigf(gsl[64 + tid]) * c0L[tid] + sigf(gsl[tid]) * tanhf_(gsl[128 + tid]);
            float hn = sigf(gsl[192 + tid]) * tanhf_(cn);
            c0L[tid] = cn;
            h0_g[b * 256 + co * 64 + tid] = hn;
        }
        gbar(ctr, (++ph) * 4);
        if (tid < 256) h0L[tid] = h0_g[b * 256 + tid];
        __syncthreads();
        // D7: layer1 gate slice
        gemv2s(wihd1, 256, whhd + 262144, 256,
               (const float4*)h0L, (const float4*)hc1f, bD1s, gsl, co);
        __syncthreads();
        // D8: elementwise l1 -> h1c1_g
        if (tid < 64) {
            float cp = hc1f[256 + co * 64 + tid];
            float cn = sigf(gsl[64 + tid]) * cp + sigf(gsl[tid]) * tanhf_(gsl[128 + tid]);
            float hn = sigf(gsl[192 + tid]) * tanhf_(cn);
            h1c1_g[b * 512 + co * 64 + tid]       = hn;
            h1c1_g[b * 512 + 256 + co * 64 + tid] = cn;
        }
        gbar(ctr, (++ph) * 4);
        if (tid < 512) hc1f[tid] = h1c1_g[b * 512 + tid];
        __syncthreads();
    }

    // ---- output: |[h1 ; partial] . proj_w + proj_b|  (one block per b) ----
    if (co == 0 && tid < 64) {
        float acc = 0.f;
        #pragma unroll
        for (int i = 0; i < 8; ++i) {
            int k = tid + 64 * i;
            float v = (k < 256) ? hc1f[k] : actP[k - 256];
            acc += v * pw[k];
        }
        acc = red64(acc);
        if (tid == 0) out[b] = fabsf(acc + pb[0]);
    }
}

// Repack w_ih_d0 [1024][257] -> [1024][260] (16B-aligned rows, zero pad).
extern "C" __global__ void repack_k(const float* __restrict__ src, float* __restrict__ dst) {
    int idx = blockIdx.x * blockDim.x + threadIdx.x;
    if (idx >= 1024 * 260) return;
    int j = idx / 260;
    int k = idx - j * 260;
    dst[idx] = (k < 257) ? src[j * 257 + k] : 0.0f;
}

extern "C" void kernel_launch(void* const* d_in, const int* in_sizes, int n_in,
                              void* d_out, int out_size, void* d_ws, size_t ws_size,
                              hipStream_t stream) {
    const float* inp   = (const float*)d_in[0];
    const float* wihe0 = (const float*)d_in[1];
    const float* wihe1 = (const float*)d_in[2];
    const float* whhe  = (const float*)d_in[3];
    const float* bihe  = (const float*)d_in[4];
    const float* bhhe  = (const float*)d_in[5];
    const float* wihd0 = (const float*)d_in[6];
    const float* wihd1 = (const float*)d_in[7];
    const float* whhd  = (const float*)d_in[8];
    const float* bihd  = (const float*)d_in[9];
    const float* bhhd  = (const float*)d_in[10];
    const float* aw1   = (const float*)d_in[11];
    const float* ab1   = (const float*)d_in[12];
    const float* aw2   = (const float*)d_in[13];
    const float* dw1   = (const float*)d_in[14];
    const float* db1   = (const float*)d_in[15];
    const float* dw2   = (const float*)d_in[16];
    const float* pw    = (const float*)d_in[17];
    const float* pb    = (const float*)d_in[18];
    float* out = (float*)d_out;
    float* ws  = (float*)d_ws;

    // ws float offsets (total 332800 floats = 1.33 MB; ws_size >= 7.7MB proven)
    const size_t WR = 0;             // wihd0 repacked: 1024*260
    const size_t H0G = 266240;       // 64*256
    const size_t H1C1G = 282624;     // 64*512
    const size_t HCTDG = 315392;     // 64*256
    const size_t BARO = 331776;      // 64 groups * 16 uints

    hipMemsetAsync((char*)d_ws + BARO * 4, 0, 4096, stream);
    repack_k<<<(1024 * 260 + 255) / 256, 256, 0, stream>>>(wihd0, ws + WR);

    const int smem = 35656 * 4;      // ~139 KB
    hipFuncSetAttribute((const void*)attn_lstm_v3,
                        hipFuncAttributeMaxDynamicSharedMemorySize, smem);
    attn_lstm_v3<<<256, NT, smem, stream>>>(
        inp, wihe0, wihe1, whhe, bihe, bhhe,
        ws + WR, wihd1, whhd, bihd, bhhd,
        aw1, ab1, aw2, dw1, db1, dw2, pw, pb,
        ws + H0G, ws + H1C1G, ws + HCTDG, (unsigned*)(ws + BARO), out);
}

// Round 4
// 7522.956 us; speedup vs baseline: 2.9589x; 2.9589x over previous
//
#include <hip/hip_runtime.h>
#include <hip/hip_fp16.h>
#include <math.h>

#define NT 1024

__device__ __forceinline__ float sigf(float x)   { return 1.0f / (1.0f + __expf(-x)); }
__device__ __forceinline__ float tanhf_(float x) { return 1.0f - 2.0f / (1.0f + __expf(2.0f * x)); }
__device__ __forceinline__ float dot4(float4 a, float4 b) {
    return a.x * b.x + a.y * b.y + a.z * b.z + a.w * b.w;
}
__device__ __forceinline__ float red16(float v) {
    v += __shfl_xor(v, 1); v += __shfl_xor(v, 2);
    v += __shfl_xor(v, 4); v += __shfl_xor(v, 8);
    return v;
}
__device__ __forceinline__ float red64(float v) {
    v += __shfl_xor(v, 1);  v += __shfl_xor(v, 2);  v += __shfl_xor(v, 4);
    v += __shfl_xor(v, 8);  v += __shfl_xor(v, 16); v += __shfl_xor(v, 32);
    return v;
}

// ---- fp16-weight GEMV, wave-per-row, K=512 fused strip (8 halfs/lane) ----
template<int RPW, bool BIAS, bool DT>
__device__ __forceinline__ void gemvh512(const __half* __restrict__ W,
                                         const float* __restrict__ act,   // 512 floats LDS
                                         const float* __restrict__ bias,  // LDS or null
                                         const __half* __restrict__ dtw, float dts,
                                         float* __restrict__ outv, int rowBase) {
    const int lane = threadIdx.x & 63;
    const float4* a4 = (const float4*)act;
    const float4 aA = a4[2 * lane], aB = a4[2 * lane + 1];
    #pragma unroll 4
    for (int rr = 0; rr < RPW; ++rr) {
        const int j = rowBase + rr;
        const uint4 wv = *((const uint4*)(W + ((size_t)j << 9)) + lane);
        const float2 f0 = __half22float2(*(const __half2*)&wv.x);
        const float2 f1 = __half22float2(*(const __half2*)&wv.y);
        const float2 f2 = __half22float2(*(const __half2*)&wv.z);
        const float2 f3 = __half22float2(*(const __half2*)&wv.w);
        float s = f0.x * aA.x + f0.y * aA.y + f1.x * aA.z + f1.y * aA.w
                + f2.x * aB.x + f2.y * aB.y + f3.x * aB.z + f3.y * aB.w;
        s = red64(s);
        if (lane == 0) {
            if (DT) s += dts * __half2float(dtw[j]);
            outv[j] = BIAS ? s + bias[j] : s;
        }
    }
}

// ---- fp16-weight GEMV, wave-per-row, K=384 strip (6 halfs/lane) ----
template<int RPW>
__device__ __forceinline__ void gemvh384(const __half* __restrict__ W,
                                         const float* __restrict__ act,   // 384 floats LDS
                                         const float* __restrict__ bias,
                                         float* __restrict__ outv, int rowBase) {
    const int lane = threadIdx.x & 63;
    const float2* a2 = (const float2*)act;
    const float2 aA = a2[3 * lane], aB = a2[3 * lane + 1], aC = a2[3 * lane + 2];
    #pragma unroll 4
    for (int rr = 0; rr < RPW; ++rr) {
        const int j = rowBase + rr;
        const uint3 wv = *((const uint3*)((const char*)W + (size_t)j * 768) + lane);
        const float2 f0 = __half22float2(*(const __half2*)&wv.x);
        const float2 f1 = __half22float2(*(const __half2*)&wv.y);
        const float2 f2 = __half22float2(*(const __half2*)&wv.z);
        float s = f0.x * aA.x + f0.y * aA.y + f1.x * aB.x + f1.y * aB.y
                + f2.x * aC.x + f2.y * aC.y;
        s = red64(s);
        if (lane == 0) outv[j] = s + bias[j];
    }
}

// ws half-offsets
#define OFF_RA   0          // aw1[:, 0:512]      64 x 512
#define OFF_RE0  32768      // [wihe0|whhe0|pad]  1024 x 384
#define OFF_RE1  425984     // [wihe1|whhe1]      1024 x 512
#define OFF_RDW1 950272     // dw1[:, 0:512]      256 x 512
#define OFF_RD0  1081344    // [wihd0[:,0:256]|whhd0] 1024 x 512
#define OFF_RDT  1605632    // wihd0[:, 256]      1024
#define OFF_RD1  1606656    // [wihd1|whhd1]      1024 x 512
#define TOT_H    2130944

// =================== v4: one block per batch element, fp16 weights =========
extern "C" __global__ void __launch_bounds__(NT)
attn_lstm_v4(const float* __restrict__ inp,  const __half* __restrict__ wsh,
             const float* __restrict__ bihe, const float* __restrict__ bhhe,
             const float* __restrict__ bihd, const float* __restrict__ bhhd,
             const float* __restrict__ aw1,  const float* __restrict__ ab1,
             const float* __restrict__ aw2,
             const float* __restrict__ dw1,  const float* __restrict__ db1,
             const float* __restrict__ dw2,
             const float* __restrict__ pw,   const float* __restrict__ pb,
             float* __restrict__ out)
{
    extern __shared__ __align__(16) float sm[];
    float* hexp   = sm;            // 16384
    float* xeT    = sm + 16384;    // 4352 (64 x 68)
    float* actHC  = sm + 20736;    // 512  [h1 | c1]
    float* actHH  = sm + 21248;    // 512  [h0 | h1]
    float* actE0  = sm + 21760;    // 384  [x_in(64) | h0(256) | 0(64)]
    float* actD0  = sm + 22144;    // 512  [partial(256) | h0(256)]
    float* gsl    = sm + 22656;    // 1024 gates
    float* hctL   = sm + 23680;    // 256
    float* scoreS = sm + 23936;    // 64
    float* aS     = sm + 24000;    // 64
    float* c0L    = sm + 24064;    // 256
    float* decin  = sm + 24320;    // 64
    float* bE0    = sm + 24400;    // 1024
    float* bE1    = sm + 25424;    // 1024
    float* bD0    = sm + 26448;    // 1024
    float* bD1    = sm + 27472;    // 1024  -> 28496 floats (~111 KB)

    const __half* RA   = wsh + OFF_RA;
    const __half* RE0  = wsh + OFF_RE0;
    const __half* RE1  = wsh + OFF_RE1;
    const __half* RDW1 = wsh + OFF_RDW1;
    const __half* RD0  = wsh + OFF_RD0;
    const __half* RDT  = wsh + OFF_RDT;
    const __half* RD1  = wsh + OFF_RD1;

    const int b   = blockIdx.x;
    const int tid = threadIdx.x;
    const int w   = tid >> 6;

    // ---- init ----
    for (int i = tid; i < 1920; i += NT) sm[20736 + i] = 0.0f;   // actHC..actD0
    if (tid < 256) c0L[tid] = 0.0f;
    {
        int j = tid;
        bE0[j] = bihe[j]        + bhhe[j];
        bE1[j] = bihe[1024 + j] + bhhe[1024 + j];
        bD0[j] = bihd[j]        + bhhd[j];
        bD1[j] = bihd[1024 + j] + bhhd[1024 + j];
    }
    const float* ib = inp + b * (64 * 65);
    for (int i = tid; i < 4096; i += NT) {
        int t = i & 63, e = i >> 6;
        xeT[e * 68 + t] = ib[t * 65 + 1 + e];
    }
    if (tid < 64) decin[tid] = ib[tid * 65];
    __syncthreads();

    const int g16 = tid >> 4, q16 = tid & 15;

    // ---- encoder attention P (input part + bias, fp32 one-time) -> regs ----
    float Preg[4], w2r[4];
    #pragma unroll
    for (int jj = 0; jj < 4; ++jj) {
        int j = q16 + 16 * jj;
        w2r[jj] = aw2[j];
        float acc = ab1[j];
        const float4* w4 = (const float4*)(aw1 + j * 576 + 512);
        const float4* x4 = (const float4*)(xeT + g16 * 68);
        #pragma unroll 4
        for (int k = 0; k < 16; ++k) acc += dot4(w4[k], x4[k]);
        Preg[jj] = acc;
    }

    // ================= encoder: 64 steps =================
    for (int t = 0; t < 64; ++t) {
        // E1: hct[j<64] = [h1;c1] . aw1[j,0:512)
        gemvh512<4, false, false>(RA, actHC, nullptr, nullptr, 0.f, hctL, w * 4);
        __syncthreads();
        // E2: score[e]
        {
            float s = 0.f;
            #pragma unroll
            for (int jj = 0; jj < 4; ++jj)
                s += tanhf_(Preg[jj] + hctL[q16 + 16 * jj]) * w2r[jj];
            s = red16(s);
            if (q16 == 0) scoreS[g16] = s;
        }
        __syncthreads();
        // E3: softmax + x_in
        if (tid < 64) {
            float v = scoreS[tid], m = v;
            #pragma unroll
            for (int d = 1; d < 64; d <<= 1) m = fmaxf(m, __shfl_xor(m, d));
            float ex = __expf(v - m), s = ex;
            #pragma unroll
            for (int d = 1; d < 64; d <<= 1) s += __shfl_xor(s, d);
            actE0[tid] = (ex / s) * xeT[tid * 68 + t];
        }
        __syncthreads();
        // E4: layer0 gates (K=384 padded)
        gemvh384<64>(RE0, actE0, bE0, gsl, w * 64);
        __syncthreads();
        // E5: elementwise l0
        if (tid < 256) {
            float cn = sigf(gsl[256 + tid]) * c0L[tid] + sigf(gsl[tid]) * tanhf_(gsl[512 + tid]);
            float hn = sigf(gsl[768 + tid]) * tanhf_(cn);
            c0L[tid] = cn; actE0[64 + tid] = hn; actHH[tid] = hn;
        }
        __syncthreads();
        // E6: layer1 gates (K=512)
        gemvh512<64, true, false>(RE1, actHH, bE1, nullptr, 0.f, gsl, w * 64);
        __syncthreads();
        // E7: elementwise l1 + h_expanded
        if (tid < 256) {
            float cp = actHC[256 + tid];
            float cn = sigf(gsl[256 + tid]) * cp + sigf(gsl[tid]) * tanhf_(gsl[512 + tid]);
            float hn = sigf(gsl[768 + tid]) * tanhf_(cn);
            actHC[tid] = hn; actHC[256 + tid] = cn;
            actHH[256 + tid] = hn;
            hexp[t * 256 + tid] = hn;
        }
        __syncthreads();
    }

    // ---- transition: zero recurrent state ----
    for (int i = tid; i < 1920; i += NT) sm[20736 + i] = 0.0f;
    if (tid < 256) c0L[tid] = 0.0f;
    __syncthreads();
    // Pd precompute (fp32 one-time) -> regs
    float Pdreg[16], w2dr[16];
    #pragma unroll
    for (int jj = 0; jj < 16; ++jj) {
        int j = q16 + 16 * jj;
        w2dr[jj] = dw2[j];
        float acc = db1[j];
        const float4* w4 = (const float4*)(dw1 + j * 768 + 512);
        const float4* x4 = (const float4*)(hexp + g16 * 256);
        #pragma unroll 4
        for (int k = 0; k < 64; ++k) acc += dot4(w4[k], x4[k]);
        Pdreg[jj] = acc;
    }
    __syncthreads();

    // ================= decoder: 64 steps =================
    const int j4 = tid >> 2, q4 = tid & 3;
    for (int t = 0; t < 64; ++t) {
        // D1: hctd[j<256] = [h1;c1] . dw1[j,0:512)
        gemvh512<16, false, false>(RDW1, actHC, nullptr, nullptr, 0.f, hctL, w * 16);
        __syncthreads();
        // D2: score[t']
        {
            float s = 0.f;
            #pragma unroll
            for (int jj = 0; jj < 16; ++jj)
                s += tanhf_(Pdreg[jj] + hctL[q16 + 16 * jj]) * w2dr[jj];
            s = red16(s);
            if (q16 == 0) scoreS[g16] = s;
        }
        __syncthreads();
        // D3: softmax -> aS
        if (tid < 64) {
            float v = scoreS[tid], m = v;
            #pragma unroll
            for (int d = 1; d < 64; d <<= 1) m = fmaxf(m, __shfl_xor(m, d));
            float ex = __expf(v - m), s = ex;
            #pragma unroll
            for (int d = 1; d < 64; d <<= 1) s += __shfl_xor(s, d);
            aS[tid] = ex / s;
        }
        __syncthreads();
        // D4: partial[c] = sum_t' hexp[t'][c] * a[t']
        {
            float acc = 0.f;
            #pragma unroll 4
            for (int i = 0; i < 16; ++i) {
                int tt = q4 + 4 * i;
                acc += hexp[tt * 256 + j4] * aS[tt];
            }
            acc += __shfl_xor(acc, 1);
            acc += __shfl_xor(acc, 2);
            if (q4 == 0) actD0[j4] = acc;
        }
        __syncthreads();
        // D5: layer0 gates (K=512 + d_t column)
        {
            float dts = decin[t];
            gemvh512<64, true, true>(RD0, actD0, bD0, RDT, dts, gsl, w * 64);
        }
        __syncthreads();
        // D6: elementwise l0
        if (tid < 256) {
            float cn = sigf(gsl[256 + tid]) * c0L[tid] + sigf(gsl[tid]) * tanhf_(gsl[512 + tid]);
            float hn = sigf(gsl[768 + tid]) * tanhf_(cn);
            c0L[tid] = cn; actD0[256 + tid] = hn; actHH[tid] = hn;
        }
        __syncthreads();
        // D7: layer1 gates (K=512)
        gemvh512<64, true, false>(RD1, actHH, bD1, nullptr, 0.f, gsl, w * 64);
        __syncthreads();
        // D8: elementwise l1
        if (tid < 256) {
            float cp = actHC[256 + tid];
            float cn = sigf(gsl[256 + tid]) * cp + sigf(gsl[tid]) * tanhf_(gsl[512 + tid]);
            float hn = sigf(gsl[768 + tid]) * tanhf_(cn);
            actHC[tid] = hn; actHC[256 + tid] = cn;
            actHH[256 + tid] = hn;
        }
        __syncthreads();
    }

    // ---- output: |[h1 ; partial] . proj_w + proj_b| ----
    if (tid < 64) {
        float acc = 0.f;
        #pragma unroll
        for (int i = 0; i < 8; ++i) {
            int k = tid + 64 * i;
            float v = (k < 256) ? actHC[k] : actD0[k - 256];
            acc += v * pw[k];
        }
        acc = red64(acc);
        if (tid == 0) out[b] = fabsf(acc + pb[0]);
    }
}

// ---- fp16 repack of all per-step weights into ws ----
extern "C" __global__ void repack16_k(const float* __restrict__ wihe0,
                                      const float* __restrict__ wihe1,
                                      const float* __restrict__ whhe,
                                      const float* __restrict__ wihd0,
                                      const float* __restrict__ wihd1,
                                      const float* __restrict__ whhd,
                                      const float* __restrict__ aw1,
                                      const float* __restrict__ dw1,
                                      __half* __restrict__ ws) {
    int idx = blockIdx.x * blockDim.x + threadIdx.x;
    if (idx >= TOT_H) return;
    float v; int o = idx;
    if (o < 32768) {                       // RA: 64 x 512
        int j = o >> 9, k = o & 511;
        v = aw1[j * 576 + k];
        ws[OFF_RA + o] = __float2half_rn(v); return;
    }
    o -= 32768;
    if (o < 393216) {                      // RE0: 1024 x 384
        int j = o / 384, k = o - j * 384;
        v = (k < 64) ? wihe0[j * 64 + k] : (k < 320 ? whhe[j * 256 + (k - 64)] : 0.0f);
        ws[OFF_RE0 + o] = __float2half_rn(v); return;
    }
    o -= 393216;
    if (o < 524288) {                      // RE1: 1024 x 512
        int j = o >> 9, k = o & 511;
        v = (k < 256) ? wihe1[j * 256 + k] : whhe[262144 + j * 256 + (k - 256)];
        ws[OFF_RE1 + o] = __float2half_rn(v); return;
    }
    o -= 524288;
    if (o < 131072) {                      // RDW1: 256 x 512
        int j = o >> 9, k = o & 511;
        v = dw1[j * 768 + k];
        ws[OFF_RDW1 + o] = __float2half_rn(v); return;
    }
    o -= 131072;
    if (o < 524288) {                      // RD0: 1024 x 512
        int j = o >> 9, k = o & 511;
        v = (k < 256) ? wihd0[j * 257 + k] : whhd[j * 256 + (k - 256)];
        ws[OFF_RD0 + o] = __float2half_rn(v); return;
    }
    o -= 524288;
    if (o < 1024) {                        // RDT: 1024
        v = wihd0[o * 257 + 256];
        ws[OFF_RDT + o] = __float2half_rn(v); return;
    }
    o -= 1024;
    {                                      // RD1: 1024 x 512
        int j = o >> 9, k = o & 511;
        v = (k < 256) ? wihd1[j * 256 + k] : whhd[262144 + j * 256 + (k - 256)];
        ws[OFF_RD1 + o] = __float2half_rn(v);
    }
}

// ======================= v1 fallback (tiny ws) =============================
extern "C" __global__ void __launch_bounds__(NT)
attn_lstm(const float* __restrict__ inp,
          const float* __restrict__ wihe0, const float* __restrict__ wihe1,
          const float* __restrict__ whhe,  const float* __restrict__ bihe,
          const float* __restrict__ bhhe,
          const float* __restrict__ wihd0, const float* __restrict__ wihd1,
          const float* __restrict__ whhd,  const float* __restrict__ bihd,
          const float* __restrict__ bhhd,
          const float* __restrict__ aw1,   const float* __restrict__ ab1,
          const float* __restrict__ aw2,
          const float* __restrict__ dw1,   const float* __restrict__ db1,
          const float* __restrict__ dw2,
          const float* __restrict__ pw,    const float* __restrict__ pb,
          float* __restrict__ out)
{
    extern __shared__ __align__(16) float sm[];
    float* h0     = sm;
    float* c0     = h0 + 256;
    float* hc1    = c0 + 256;
    float* full   = hc1 + 512;
    float* gates  = full + 260;
    float* scoreS = gates + 1024;
    float* aS     = scoreS + 64;
    float* hctS   = aS + 64;
    float* decin  = hctS + 256;
    float* hexp   = decin + 64;
    float* xeT    = hexp + 16384;

    const int b   = blockIdx.x;
    const int tid = threadIdx.x;

    for (int i = tid; i < 1284; i += NT) sm[i] = 0.0f;
    const float* ib = inp + b * (64 * 65);
    for (int i = tid; i < 4096; i += NT) {
        int t = i & 63, e = i >> 6;
        xeT[e * 68 + t] = ib[t * 65 + 1 + e];
    }
    if (tid < 64) decin[tid] = ib[tid * 65];
    __syncthreads();

    const int g16 = tid >> 4;
    const int q16 = tid & 15;

    float Preg[4], w2r[4];
    #pragma unroll
    for (int jj = 0; jj < 4; ++jj) {
        int j = q16 + 16 * jj;
        w2r[jj] = aw2[j];
        float acc = ab1[j];
        const float4* w4 = (const float4*)(aw1 + j * 576 + 512);
        const float4* x4 = (const float4*)(xeT + g16 * 68);
        #pragma unroll 4
        for (int k = 0; k < 16; ++k) acc += dot4(w4[k], x4[k]);
        Preg[jj] = acc;
    }

    for (int t = 0; t < 64; ++t) {
        {
            const float* wr = aw1 + g16 * 576;
            float acc = 0.f;
            #pragma unroll 8
            for (int i = 0; i < 32; ++i) {
                int k = q16 + 16 * i;
                acc += hc1[k] * wr[k];
            }
            acc = red16(acc);
            if (q16 == 0) hctS[g16] = acc;
        }
        __syncthreads();
        {
            float s = 0.f;
            #pragma unroll
            for (int jj = 0; jj < 4; ++jj)
                s += tanhf_(Preg[jj] + hctS[q16 + 16 * jj]) * w2r[jj];
            s = red16(s);
            if (q16 == 0) scoreS[g16] = s;
        }
        __syncthreads();
        if (tid < 64) {
            float v = scoreS[tid], m = v;
            #pragma unroll
            for (int d = 1; d < 64; d <<= 1) m = fmaxf(m, __shfl_xor(m, d));
            float ex = __expf(v - m), s = ex;
            #pragma unroll
            for (int d = 1; d < 64; d <<= 1) s += __shfl_xor(s, d);
            full[tid] = (ex / s) * xeT[tid * 68 + t];
        }
        __syncthreads();
        {
            int j = tid;
            float acc = bihe[j] + bhhe[j];
            const float4* wi = (const float4*)(wihe0 + (j << 6));
            const float4* xf = (const float4*)full;
            #pragma unroll 4
            for (int k = 0; k < 16; ++k) acc += dot4(wi[k], xf[k]);
            const float4* wh = (const float4*)(whhe + (j << 8));
            const float4* h4 = (const float4*)h0;
            #pragma unroll 4
            for (int k = 0; k < 64; ++k) acc += dot4(wh[k], h4[k]);
            gates[j] = acc;
        }
        __syncthreads();
        if (tid < 256) {
            float cn = sigf(gates[256 + tid]) * c0[tid] + sigf(gates[tid]) * tanhf_(gates[512 + tid]);
            float hn = sigf(gates[768 + tid]) * tanhf_(cn);
            c0[tid] = cn; h0[tid] = hn;
        }
        __syncthreads();
        {
            int j = tid;
            float acc = bihe[1024 + j] + bhhe[1024 + j];
            const float4* wi = (const float4*)(wihe1 + (j << 8));
            const float4* h4 = (const float4*)h0;
            #pragma unroll 4
            for (int k = 0; k < 64; ++k) acc += dot4(wi[k], h4[k]);
            const float4* wh = (const float4*)(whhe + 262144 + (j << 8));
            const float4* h14 = (const float4*)hc1;
            #pragma unroll 4
            for (int k = 0; k < 64; ++k) acc += dot4(wh[k], h14[k]);
            gates[j] = acc;
        }
        __syncthreads();
        if (tid < 256) {
            float cn = sigf(gates[256 + tid]) * hc1[256 + tid] + sigf(gates[tid]) * tanhf_(gates[512 + tid]);
            float hn = sigf(gates[768 + tid]) * tanhf_(cn);
            hc1[256 + tid] = cn; hc1[tid] = hn;
            hexp[t * 256 + tid] = hn;
        }
        __syncthreads();
    }

    sm[tid] = 0.0f;
    float Pdreg[16], w2dr[16];
    #pragma unroll
    for (int jj = 0; jj < 16; ++jj) {
        int j = q16 + 16 * jj;
        w2dr[jj] = dw2[j];
        float acc = db1[j];
        const float4* w4 = (const float4*)(dw1 + j * 768 + 512);
        const float4* x4 = (const float4*)(hexp + g16 * 256);
        #pragma unroll 4
        for (int k = 0; k < 64; ++k) acc += dot4(w4[k], x4[k]);
        Pdreg[jj] = acc;
    }
    __syncthreads();

    const int j4 = tid >> 2;
    const int q4 = tid & 3;
    for (int t = 0; t < 64; ++t) {
        {
            const float4* w4 = (const float4*)(dw1 + j4 * 768 + q4 * 128);
            const float4* x4 = (const float4*)(hc1 + q4 * 128);
            float acc = 0.f;
            #pragma unroll 4
            for (int i = 0; i < 32; ++i) acc += dot4(w4[i], x4[i]);
            acc += __shfl_xor(acc, 1);
            acc += __shfl_xor(acc, 2);
            if (q4 == 0) hctS[j4] = acc;
        }
        __syncthreads();
        {
            float s = 0.f;
            #pragma unroll
            for (int jj = 0; jj < 16; ++jj)
                s += tanhf_(Pdreg[jj] + hctS[q16 + 16 * jj]) * w2dr[jj];
            s = red16(s);
            if (q16 == 0) scoreS[g16] = s;
        }
        __syncthreads();
        if (tid < 64) {
            float v = scoreS[tid], m = v;
            #pragma unroll
            for (int d = 1; d < 64; d <<= 1) m = fmaxf(m, __shfl_xor(m, d));
            float ex = __expf(v - m), s = ex;
            #pragma unroll
            for (int d = 1; d < 64; d <<= 1) s += __shfl_xor(s, d);
            aS[tid] = ex / s;
            if (tid == 0) full[256] = decin[t];
        }
        __syncthreads();
        {
            float acc = 0.f;
            #pragma unroll 4
            for (int i = 0; i < 16; ++i) {
                int tt = q4 + 4 * i;
                acc += hexp[tt * 256 + j4] * aS[tt];
            }
            acc += __shfl_xor(acc, 1);
            acc += __shfl_xor(acc, 2);
            if (q4 == 0) full[j4] = acc;
        }
        __syncthreads();
        {
            int j = tid;
            float acc = bihd[j] + bhhd[j];
            const float* wi = wihd0 + j * 257;
            #pragma unroll 8
            for (int k = 0; k < 257; ++k) acc += wi[k] * full[k];
            const float4* wh = (const float4*)(whhd + (j << 8));
            const float4* h4 = (const float4*)h0;
            #pragma unroll 4
            for (int k = 0; k < 64; ++k) acc += dot4(wh[k], h4[k]);
            gates[j] = acc;
        }
        __syncthreads();
        if (tid < 256) {
            float cn = sigf(gates[256 + tid]) * c0[tid] + sigf(gates[tid]) * tanhf_(gates[512 + tid]);
            float hn = sigf(gates[768 + tid]) * tanhf_(cn);
            c0[tid] = cn; h0[tid] = hn;
        }
        __syncthreads();
        {
            int j = tid;
            float acc = bihd[1024 + j] + bhhd[1024 + j];
            const float4* wi = (const float4*)(wihd1 + (j << 8));
            const float4* h4 = (const float4*)h0;
            #pragma unroll 4
            for (int k = 0; k < 64; ++k) acc += dot4(wi[k], h4[k]);
            const float4* wh = (const float4*)(whhd + 262144 + (j << 8));
            const float4* h14 = (const float4*)hc1;
            #pragma unroll 4
            for (int k = 0; k < 64; ++k) acc += dot4(wh[k], h14[k]);
            gates[j] = acc;
        }
        __syncthreads();
        if (tid < 256) {
            float cn = sigf(gates[256 + tid]) * hc1[256 + tid] + sigf(gates[tid]) * tanhf_(gates[512 + tid]);
            float hn = sigf(gates[768 + tid]) * tanhf_(cn);
            hc1[256 + tid] = cn; hc1[tid] = hn;
        }
        __syncthreads();
    }

    if (tid < 64) {
        float acc = 0.f;
        #pragma unroll
        for (int i = 0; i < 8; ++i) {
            int k = tid + 64 * i;
            float v = (k < 256) ? hc1[k] : full[k - 256];
            acc += v * pw[k];
        }
        acc = red64(acc);
        if (tid == 0) out[b] = fabsf(acc + pb[0]);
    }
}

extern "C" void kernel_launch(void* const* d_in, const int* in_sizes, int n_in,
                              void* d_out, int out_size, void* d_ws, size_t ws_size,
                              hipStream_t stream) {
    const float* inp   = (const float*)d_in[0];
    const float* wihe0 = (const float*)d_in[1];
    const float* wihe1 = (const float*)d_in[2];
    const float* whhe  = (const float*)d_in[3];
    const float* bihe  = (const float*)d_in[4];
    const float* bhhe  = (const float*)d_in[5];
    const float* wihd0 = (const float*)d_in[6];
    const float* wihd1 = (const float*)d_in[7];
    const float* whhd  = (const float*)d_in[8];
    const float* bihd  = (const float*)d_in[9];
    const float* bhhd  = (const float*)d_in[10];
    const float* aw1   = (const float*)d_in[11];
    const float* ab1   = (const float*)d_in[12];
    const float* aw2   = (const float*)d_in[13];
    const float* dw1   = (const float*)d_in[14];
    const float* db1   = (const float*)d_in[15];
    const float* dw2   = (const float*)d_in[16];
    const float* pw    = (const float*)d_in[17];
    const float* pb    = (const float*)d_in[18];
    float* out = (float*)d_out;

    if (ws_size >= (size_t)TOT_H * sizeof(__half)) {
        __half* wsh = (__half*)d_ws;
        repack16_k<<<(TOT_H + 255) / 256, 256, 0, stream>>>(
            wihe0, wihe1, whhe, wihd0, wihd1, whhd, aw1, dw1, wsh);
        const int smem = 28496 * 4;   // ~111 KB
        hipFuncSetAttribute((const void*)attn_lstm_v4,
                            hipFuncAttributeMaxDynamicSharedMemorySize, smem);
        attn_lstm_v4<<<64, NT, smem, stream>>>(
            inp, wsh, bihe, bhhe, bihd, bhhd,
            aw1, ab1, aw2, dw1, db1, dw2, pw, pb, out);
        return;
    }

    // fallback: fp32 v1 (no workspace needed)
    const int smem_bytes = 23492 * sizeof(float);
    hipFuncSetAttribute((const void*)attn_lstm,
                        hipFuncAttributeMaxDynamicSharedMemorySize, smem_bytes);
    attn_lstm<<<64, NT, smem_bytes, stream>>>(
        inp, wihe0, wihe1, whhe, bihe, bhhe,
        wihd0, wihd1, whhd, bihd, bhhd,
        aw1, ab1, aw2, dw1, db1, dw2, pw, pb, out);
}

// Round 5
// 4253.142 us; speedup vs baseline: 5.2336x; 1.7688x over previous
//
#include <hip/hip_runtime.h>
#include <hip/hip_fp16.h>
#include <math.h>

#define NT 1024

typedef _Float16 h2v __attribute__((ext_vector_type(2)));
union H8 { uint4 u; h2v h[4]; };

__device__ __forceinline__ float sigf(float x)   { return 1.0f / (1.0f + __expf(-x)); }
__device__ __forceinline__ float tanhf_(float x) { return 1.0f - 2.0f / (1.0f + __expf(2.0f * x)); }
__device__ __forceinline__ float dot4(float4 a, float4 b) {
    return a.x * b.x + a.y * b.y + a.z * b.z + a.w * b.w;
}
__device__ __forceinline__ float red16(float v) {
    v += __shfl_xor(v, 1); v += __shfl_xor(v, 2);
    v += __shfl_xor(v, 4); v += __shfl_xor(v, 8);
    return v;
}
__device__ __forceinline__ float red64(float v) {
    v += __shfl_xor(v, 1);  v += __shfl_xor(v, 2);  v += __shfl_xor(v, 4);
    v += __shfl_xor(v, 8);  v += __shfl_xor(v, 16); v += __shfl_xor(v, 32);
    return v;
}
__device__ __forceinline__ float dot2h(h2v a, h2v b, float c) {
#if __has_builtin(__builtin_amdgcn_fdot2)
    return __builtin_amdgcn_fdot2(a, b, c, false);
#else
    return c + (float)a[0] * (float)b[0] + (float)a[1] * (float)b[1];
#endif
}

// ws half-offsets (permuted-packed weights)
#define OFF_RA   0          // aw1[:, 0:512]          64 x 512
#define OFF_RE0  32768      // [wihe0|whhe0|pad]      1024 x 384
#define OFF_RE1  425984     // [wihe1|whhe1]          1024 x 512
#define OFF_RDW1 950272     // dw1[:, 0:512]          256 x 512
#define OFF_RD0  1081344    // [wihd0[:,0:256]|whhd0] 1024 x 512
#define OFF_RDT  1605632    // wihd0[:, 256]          1024
#define OFF_RD1  1606656    // [wihd1|whhd1]          1024 x 512
#define TOT_H    2130944

// K=512 GEMV: 16 lanes/row, 4 rows/wave-iter. Weight row = 1KB, lane q reads
// halfs [32q,32q+32) (contiguous 64B); act chunk c = halfs [8q+128c, +8).
template<int ITERS, bool BIAS, bool DT>
__device__ __forceinline__ void gemv512(const __half* __restrict__ W,
                                        const __half* __restrict__ act,
                                        const float* __restrict__ bias,
                                        const __half* __restrict__ rdt, float dts,
                                        float* __restrict__ outg, int rowBase) {
    const int lane = threadIdx.x & 63;
    const int q = lane & 15, g = lane >> 4;
    H8 a0, a1, a2, a3;
    a0.u = *(const uint4*)(act + 8 * q);
    a1.u = *(const uint4*)(act + 8 * q + 128);
    a2.u = *(const uint4*)(act + 8 * q + 256);
    a3.u = *(const uint4*)(act + 8 * q + 384);
    #pragma unroll 2
    for (int it = 0; it < ITERS; ++it) {
        const int j = rowBase + it * 4 + g;
        const uint4* wp = (const uint4*)(W + ((size_t)j << 9) + 32 * q);
        H8 w0, w1, w2, w3;
        w0.u = wp[0]; w1.u = wp[1]; w2.u = wp[2]; w3.u = wp[3];
        float s0 = 0.f, s1 = 0.f;
        #pragma unroll
        for (int i = 0; i < 4; ++i) {
            s0 = dot2h(w0.h[i], a0.h[i], s0);
            s1 = dot2h(w1.h[i], a1.h[i], s1);
            s0 = dot2h(w2.h[i], a2.h[i], s0);
            s1 = dot2h(w3.h[i], a3.h[i], s1);
        }
        float s = s0 + s1;
        s += __shfl_xor(s, 1); s += __shfl_xor(s, 2);
        s += __shfl_xor(s, 4); s += __shfl_xor(s, 8);
        if (q == 0) {
            if (DT) s += dts * (float)rdt[j];
            outg[j] = BIAS ? s + bias[j] : s;
        }
    }
}

// K=384 GEMV: lane q reads halfs [24q,24q+24) (48B); act chunks c=0..2.
template<int ITERS>
__device__ __forceinline__ void gemv384(const __half* __restrict__ W,
                                        const __half* __restrict__ act,
                                        const float* __restrict__ bias,
                                        float* __restrict__ outg, int rowBase) {
    const int lane = threadIdx.x & 63;
    const int q = lane & 15, g = lane >> 4;
    H8 a0, a1, a2;
    a0.u = *(const uint4*)(act + 8 * q);
    a1.u = *(const uint4*)(act + 8 * q + 128);
    a2.u = *(const uint4*)(act + 8 * q + 256);
    #pragma unroll 2
    for (int it = 0; it < ITERS; ++it) {
        const int j = rowBase + it * 4 + g;
        const uint4* wp = (const uint4*)(W + (size_t)j * 384 + 24 * q);
        H8 w0, w1, w2;
        w0.u = wp[0]; w1.u = wp[1]; w2.u = wp[2];
        float s0 = 0.f, s1 = 0.f;
        #pragma unroll
        for (int i = 0; i < 4; ++i) {
            s0 = dot2h(w0.h[i], a0.h[i], s0);
            s1 = dot2h(w1.h[i], a1.h[i], s1);
            s0 = dot2h(w2.h[i], a2.h[i], s0);
        }
        float s = s0 + s1;
        s += __shfl_xor(s, 1); s += __shfl_xor(s, 2);
        s += __shfl_xor(s, 4); s += __shfl_xor(s, 8);
        if (q == 0) outg[j] = s + bias[j];
    }
}

// LDS float offsets
#define L_HEXP   0        // 16384
#define L_XET    16384    // 4352 (64 x 68)
#define L_GSL    20736    // 1024
#define L_HCT    21760    // 256
#define L_SCORE  22016    // 64
#define L_AS     22080    // 64
#define L_C0     22144    // 256
#define L_HC1F   22400    // 512
#define L_DECIN  22912    // 64
#define L_PARTF  22976    // 256
#define L_BE0    23232    // 1024
#define L_BE1    24256    // 1024
#define L_BD0    25280    // 1024
#define L_BD1    26304    // 1024
#define L_AHC    27328    // 512 halfs = 256 floats  [h1|c1]
#define L_AE0    27584    // 384 halfs = 192         [x_in|h0|0]
#define L_AHH    27776    // 512 halfs = 256         [h0|h1]
#define L_AD0    28032    // 512 halfs = 256         [partial|h0]
#define L_RDT    28288    // 1024 halfs = 512
#define L_TOT    28800    // floats -> 115200 B

extern "C" __global__ void __launch_bounds__(NT)
attn_lstm_v5(const float* __restrict__ inp,  const __half* __restrict__ wsh,
             const float* __restrict__ bihe, const float* __restrict__ bhhe,
             const float* __restrict__ bihd, const float* __restrict__ bhhd,
             const float* __restrict__ aw1,  const float* __restrict__ ab1,
             const float* __restrict__ aw2,
             const float* __restrict__ dw1,  const float* __restrict__ db1,
             const float* __restrict__ dw2,
             const float* __restrict__ pw,   const float* __restrict__ pb,
             float* __restrict__ out)
{
    extern __shared__ __align__(16) float sm[];
    float* hexp   = sm + L_HEXP;
    float* xeT    = sm + L_XET;
    float* gsl    = sm + L_GSL;
    float* hctL   = sm + L_HCT;
    float* scoreS = sm + L_SCORE;
    float* aS     = sm + L_AS;
    float* c0L    = sm + L_C0;
    float* hc1f   = sm + L_HC1F;
    float* decin  = sm + L_DECIN;
    float* partF  = sm + L_PARTF;
    float* bE0    = sm + L_BE0;
    float* bE1    = sm + L_BE1;
    float* bD0    = sm + L_BD0;
    float* bD1    = sm + L_BD1;
    __half* aHC   = (__half*)(sm + L_AHC);
    __half* aE0   = (__half*)(sm + L_AE0);
    __half* aHH   = (__half*)(sm + L_AHH);
    __half* aD0   = (__half*)(sm + L_AD0);
    __half* rdtL  = (__half*)(sm + L_RDT);

    const __half* RA   = wsh + OFF_RA;
    const __half* RE0  = wsh + OFF_RE0;
    const __half* RE1  = wsh + OFF_RE1;
    const __half* RDW1 = wsh + OFF_RDW1;
    const __half* RD0  = wsh + OFF_RD0;
    const __half* RD1  = wsh + OFF_RD1;

    const int b   = blockIdx.x;
    const int tid = threadIdx.x;
    const int w   = tid >> 6;

    // ---- init: zero state + half buffers; stage inputs, biases, rdt ----
    for (int i = tid; i < (L_BE0 - L_C0); i += NT) sm[L_C0 + i] = 0.0f;
    for (int i = tid; i < (L_RDT - L_AHC); i += NT) sm[L_AHC + i] = 0.0f;
    if (tid < 512) sm[L_RDT + tid] = ((const float*)(wsh + OFF_RDT))[tid];  // raw copy of 1024 halfs
    {
        int j = tid;
        bE0[j] = bihe[j]        + bhhe[j];
        bE1[j] = bihe[1024 + j] + bhhe[1024 + j];
        bD0[j] = bihd[j]        + bhhd[j];
        bD1[j] = bihd[1024 + j] + bhhd[1024 + j];
    }
    const float* ib = inp + b * (64 * 65);
    for (int i = tid; i < 4096; i += NT) {
        int t = i & 63, e = i >> 6;
        xeT[e * 68 + t] = ib[t * 65 + 1 + e];
    }
    if (tid < 64) decin[tid] = ib[tid * 65];
    __syncthreads();

    const int g16 = tid >> 4, q16 = tid & 15;

    // ---- encoder attention P (input part + bias, fp32 one-time) -> regs ----
    float Preg[4], w2r[4];
    #pragma unroll
    for (int jj = 0; jj < 4; ++jj) {
        int j = q16 + 16 * jj;
        w2r[jj] = aw2[j];
        float acc = ab1[j];
        const float4* w4 = (const float4*)(aw1 + j * 576 + 512);
        const float4* x4 = (const float4*)(xeT + g16 * 68);
        #pragma unroll 4
        for (int k = 0; k < 16; ++k) acc += dot4(w4[k], x4[k]);
        Preg[jj] = acc;
    }

    // ================= encoder: 64 steps =================
    for (int t = 0; t < 64; ++t) {
        // E1: hct[j<64] = [h1;c1] . aw1[j,0:512)
        gemv512<1, false, false>(RA, aHC, nullptr, nullptr, 0.f, hctL, w * 4);
        __syncthreads();
        // E2: score[e]
        {
            float s = 0.f;
            #pragma unroll
            for (int jj = 0; jj < 4; ++jj)
                s += tanhf_(Preg[jj] + hctL[q16 + 16 * jj]) * w2r[jj];
            s = red16(s);
            if (q16 == 0) scoreS[g16] = s;
        }
        __syncthreads();
        // E3: softmax + x_in (half)
        if (tid < 64) {
            float v = scoreS[tid], m = v;
            #pragma unroll
            for (int d = 1; d < 64; d <<= 1) m = fmaxf(m, __shfl_xor(m, d));
            float ex = __expf(v - m), s = ex;
            #pragma unroll
            for (int d = 1; d < 64; d <<= 1) s += __shfl_xor(s, d);
            aE0[tid] = __float2half((ex / s) * xeT[tid * 68 + t]);
        }
        __syncthreads();
        // E4: layer0 gates (K=384)
        gemv384<16>(RE0, aE0, bE0, gsl, w * 64);
        __syncthreads();
        // E5: elementwise l0
        if (tid < 256) {
            float cn = sigf(gsl[256 + tid]) * c0L[tid] + sigf(gsl[tid]) * tanhf_(gsl[512 + tid]);
            float hn = sigf(gsl[768 + tid]) * tanhf_(cn);
            c0L[tid] = cn;
            __half hh = __float2half(hn);
            aE0[64 + tid] = hh; aHH[tid] = hh;
        }
        __syncthreads();
        // E6: layer1 gates (K=512)
        gemv512<16, true, false>(RE1, aHH, bE1, nullptr, 0.f, gsl, w * 64);
        __syncthreads();
        // E7: elementwise l1 + h_expanded
        if (tid < 256) {
            float cp = hc1f[256 + tid];
            float cn = sigf(gsl[256 + tid]) * cp + sigf(gsl[tid]) * tanhf_(gsl[512 + tid]);
            float hn = sigf(gsl[768 + tid]) * tanhf_(cn);
            hc1f[tid] = hn; hc1f[256 + tid] = cn;
            __half hh = __float2half(hn);
            aHC[tid] = hh; aHC[256 + tid] = __float2half(cn);
            aHH[256 + tid] = hh;
            hexp[t * 256 + tid] = hn;
        }
        __syncthreads();
    }

    // ---- transition: zero recurrent state; Pd precompute -> regs ----
    if (tid < 256) { c0L[tid] = 0.0f; hc1f[tid] = 0.0f; hc1f[256 + tid] = 0.0f; }
    for (int i = tid; i < (L_RDT - L_AHC); i += NT) sm[L_AHC + i] = 0.0f;
    __syncthreads();
    float Pdreg[16], w2dr[16];
    #pragma unroll
    for (int jj = 0; jj < 16; ++jj) {
        int j = q16 + 16 * jj;
        w2dr[jj] = dw2[j];
        float acc = db1[j];
        const float4* w4 = (const float4*)(dw1 + j * 768 + 512);
        const float4* x4 = (const float4*)(hexp + g16 * 256);
        #pragma unroll 4
        for (int k = 0; k < 64; ++k) acc += dot4(w4[k], x4[k]);
        Pdreg[jj] = acc;
    }
    __syncthreads();

    // ================= decoder: 64 steps =================
    const int j4 = tid >> 2, q4 = tid & 3;
    for (int t = 0; t < 64; ++t) {
        // D1: hctd[j<256] = [h1;c1] . dw1[j,0:512)
        gemv512<4, false, false>(RDW1, aHC, nullptr, nullptr, 0.f, hctL, w * 16);
        __syncthreads();
        // D2: score[t']
        {
            float s = 0.f;
            #pragma unroll
            for (int jj = 0; jj < 16; ++jj)
                s += tanhf_(Pdreg[jj] + hctL[q16 + 16 * jj]) * w2dr[jj];
            s = red16(s);
            if (q16 == 0) scoreS[g16] = s;
        }
        __syncthreads();
        // D3: softmax -> aS
        if (tid < 64) {
            float v = scoreS[tid], m = v;
            #pragma unroll
            for (int d = 1; d < 64; d <<= 1) m = fmaxf(m, __shfl_xor(m, d));
            float ex = __expf(v - m), s = ex;
            #pragma unroll
            for (int d = 1; d < 64; d <<= 1) s += __shfl_xor(s, d);
            aS[tid] = ex / s;
        }
        __syncthreads();
        // D4: partial[c] = sum_t' hexp[t'][c] * a[t']
        {
            float acc = 0.f;
            #pragma unroll 4
            for (int i = 0; i < 16; ++i) {
                int tt = q4 + 4 * i;
                acc += hexp[tt * 256 + j4] * aS[tt];
            }
            acc += __shfl_xor(acc, 1);
            acc += __shfl_xor(acc, 2);
            if (q4 == 0) { aD0[j4] = __float2half(acc); partF[j4] = acc; }
        }
        __syncthreads();
        // D5: layer0 gates (K=512 + d_t column)
        gemv512<16, true, true>(RD0, aD0, bD0, rdtL, decin[t], gsl, w * 64);
        __syncthreads();
        // D6: elementwise l0
        if (tid < 256) {
            float cn = sigf(gsl[256 + tid]) * c0L[tid] + sigf(gsl[tid]) * tanhf_(gsl[512 + tid]);
            float hn = sigf(gsl[768 + tid]) * tanhf_(cn);
            c0L[tid] = cn;
            __half hh = __float2half(hn);
            aD0[256 + tid] = hh; aHH[tid] = hh;
        }
        __syncthreads();
        // D7: layer1 gates (K=512)
        gemv512<16, true, false>(RD1, aHH, bD1, nullptr, 0.f, gsl, w * 64);
        __syncthreads();
        // D8: elementwise l1
        if (tid < 256) {
            float cp = hc1f[256 + tid];
            float cn = sigf(gsl[256 + tid]) * cp + sigf(gsl[tid]) * tanhf_(gsl[512 + tid]);
            float hn = sigf(gsl[768 + tid]) * tanhf_(cn);
            hc1f[tid] = hn; hc1f[256 + tid] = cn;
            __half hh = __float2half(hn);
            aHC[tid] = hh; aHC[256 + tid] = __float2half(cn);
            aHH[256 + tid] = hh;
        }
        __syncthreads();
    }

    // ---- output: |[h1 ; partial] . proj_w + proj_b| ----
    if (tid < 64) {
        float acc = 0.f;
        #pragma unroll
        for (int i = 0; i < 8; ++i) {
            int k = tid + 64 * i;
            float v = (k < 256) ? hc1f[k] : partF[k - 256];
            acc += v * pw[k];
        }
        acc = red64(acc);
        if (tid == 0) out[b] = fabsf(acc + pb[0]);
    }
}

// ---- fp16 permuted repack ----
// K512 rows: packed[j][32q+8c+e] = orig[j][8q+128c+e]   (q<16,c<4,e<8)
// K384 rows: packed[j][24q+8c+e] = orig[j][8q+128c+e]   (q<16,c<3,e<8)
extern "C" __global__ void repack16b(const float* __restrict__ wihe0,
                                     const float* __restrict__ wihe1,
                                     const float* __restrict__ whhe,
                                     const float* __restrict__ wihd0,
                                     const float* __restrict__ wihd1,
                                     const float* __restrict__ whhd,
                                     const float* __restrict__ aw1,
                                     const float* __restrict__ dw1,
                                     __half* __restrict__ ws) {
    int idx = blockIdx.x * blockDim.x + threadIdx.x;
    if (idx >= TOT_H) return;
    int o = idx; float v;
    if (o < 32768) {                       // RA: 64 x 512
        int j = o >> 9, p = o & 511;
        int q = p >> 5, r = p & 31, c = r >> 3, e = r & 7;
        int k = 8 * q + 128 * c + e;
        v = aw1[j * 576 + k];
        ws[OFF_RA + o] = __float2half_rn(v); return;
    }
    o -= 32768;
    if (o < 393216) {                      // RE0: 1024 x 384
        int j = o / 384, p = o - j * 384;
        int q = p / 24, r = p - q * 24, c = r >> 3, e = r & 7;
        int k = 8 * q + 128 * c + e;
        v = (k < 64) ? wihe0[j * 64 + k] : (k < 320 ? whhe[j * 256 + (k - 64)] : 0.0f);
        ws[OFF_RE0 + o] = __float2half_rn(v); return;
    }
    o -= 393216;
    if (o < 524288) {                      // RE1: 1024 x 512
        int j = o >> 9, p = o & 511;
        int q = p >> 5, r = p & 31, c = r >> 3, e = r & 7;
        int k = 8 * q + 128 * c + e;
        v = (k < 256) ? wihe1[j * 256 + k] : whhe[262144 + j * 256 + (k - 256)];
        ws[OFF_RE1 + o] = __float2half_rn(v); return;
    }
    o -= 524288;
    if (o < 131072) {                      // RDW1: 256 x 512
        int j = o >> 9, p = o & 511;
        int q = p >> 5, r = p & 31, c = r >> 3, e = r & 7;
        int k = 8 * q + 128 * c + e;
        v = dw1[j * 768 + k];
        ws[OFF_RDW1 + o] = __float2half_rn(v); return;
    }
    o -= 131072;
    if (o < 524288) {                      // RD0: 1024 x 512
        int j = o >> 9, p = o & 511;
        int q = p >> 5, r = p & 31, c = r >> 3, e = r & 7;
        int k = 8 * q + 128 * c + e;
        v = (k < 256) ? wihd0[j * 257 + k] : whhd[j * 256 + (k - 256)];
        ws[OFF_RD0 + o] = __float2half_rn(v); return;
    }
    o -= 524288;
    if (o < 1024) {                        // RDT: 1024
        v = wihd0[o * 257 + 256];
        ws[OFF_RDT + o] = __float2half_rn(v); return;
    }
    o -= 1024;
    {                                      // RD1: 1024 x 512
        int j = o >> 9, p = o & 511;
        int q = p >> 5, r = p & 31, c = r >> 3, e = r & 7;
        int k = 8 * q + 128 * c + e;
        v = (k < 256) ? wihd1[j * 256 + k] : whhd[262144 + j * 256 + (k - 256)];
        ws[OFF_RD1 + o] = __float2half_rn(v);
    }
}

// ======================= v1 fp32 fallback (tiny ws) ========================
extern "C" __global__ void __launch_bounds__(NT)
attn_lstm(const float* __restrict__ inp,
          const float* __restrict__ wihe0, const float* __restrict__ wihe1,
          const float* __restrict__ whhe,  const float* __restrict__ bihe,
          const float* __restrict__ bhhe,
          const float* __restrict__ wihd0, const float* __restrict__ wihd1,
          const float* __restrict__ whhd,  const float* __restrict__ bihd,
          const float* __restrict__ bhhd,
          const float* __restrict__ aw1,   const float* __restrict__ ab1,
          const float* __restrict__ aw2,
          const float* __restrict__ dw1,   const float* __restrict__ db1,
          const float* __restrict__ dw2,
          const float* __restrict__ pw,    const float* __restrict__ pb,
          float* __restrict__ out)
{
    extern __shared__ __align__(16) float sm[];
    float* h0     = sm;
    float* c0     = h0 + 256;
    float* hc1    = c0 + 256;
    float* full   = hc1 + 512;
    float* gates  = full + 260;
    float* scoreS = gates + 1024;
    float* aS     = scoreS + 64;
    float* hctS   = aS + 64;
    float* decin  = hctS + 256;
    float* hexp   = decin + 64;
    float* xeT    = hexp + 16384;

    const int b   = blockIdx.x;
    const int tid = threadIdx.x;

    for (int i = tid; i < 1284; i += NT) sm[i] = 0.0f;
    const float* ib = inp + b * (64 * 65);
    for (int i = tid; i < 4096; i += NT) {
        int t = i & 63, e = i >> 6;
        xeT[e * 68 + t] = ib[t * 65 + 1 + e];
    }
    if (tid < 64) decin[tid] = ib[tid * 65];
    __syncthreads();

    const int g16 = tid >> 4;
    const int q16 = tid & 15;

    float Preg[4], w2r[4];
    #pragma unroll
    for (int jj = 0; jj < 4; ++jj) {
        int j = q16 + 16 * jj;
        w2r[jj] = aw2[j];
        float acc = ab1[j];
        const float4* w4 = (const float4*)(aw1 + j * 576 + 512);
        const float4* x4 = (const float4*)(xeT + g16 * 68);
        #pragma unroll 4
        for (int k = 0; k < 16; ++k) acc += dot4(w4[k], x4[k]);
        Preg[jj] = acc;
    }

    for (int t = 0; t < 64; ++t) {
        {
            const float* wr = aw1 + g16 * 576;
            float acc = 0.f;
            #pragma unroll 8
            for (int i = 0; i < 32; ++i) {
                int k = q16 + 16 * i;
                acc += hc1[k] * wr[k];
            }
            acc = red16(acc);
            if (q16 == 0) hctS[g16] = acc;
        }
        __syncthreads();
        {
            float s = 0.f;
            #pragma unroll
            for (int jj = 0; jj < 4; ++jj)
                s += tanhf_(Preg[jj] + hctS[q16 + 16 * jj]) * w2r[jj];
            s = red16(s);
            if (q16 == 0) scoreS[g16] = s;
        }
        __syncthreads();
        if (tid < 64) {
            float v = scoreS[tid], m = v;
            #pragma unroll
            for (int d = 1; d < 64; d <<= 1) m = fmaxf(m, __shfl_xor(m, d));
            float ex = __expf(v - m), s = ex;
            #pragma unroll
            for (int d = 1; d < 64; d <<= 1) s += __shfl_xor(s, d);
            full[tid] = (ex / s) * xeT[tid * 68 + t];
        }
        __syncthreads();
        {
            int j = tid;
            float acc = bihe[j] + bhhe[j];
            const float4* wi = (const float4*)(wihe0 + (j << 6));
            const float4* xf = (const float4*)full;
            #pragma unroll 4
            for (int k = 0; k < 16; ++k) acc += dot4(wi[k], xf[k]);
            const float4* wh = (const float4*)(whhe + (j << 8));
            const float4* h4 = (const float4*)h0;
            #pragma unroll 4
            for (int k = 0; k < 64; ++k) acc += dot4(wh[k], h4[k]);
            gates[j] = acc;
        }
        __syncthreads();
        if (tid < 256) {
            float cn = sigf(gates[256 + tid]) * c0[tid] + sigf(gates[tid]) * tanhf_(gates[512 + tid]);
            float hn = sigf(gates[768 + tid]) * tanhf_(cn);
            c0[tid] = cn; h0[tid] = hn;
        }
        __syncthreads();
        {
            int j = tid;
            float acc = bihe[1024 + j] + bhhe[1024 + j];
            const float4* wi = (const float4*)(wihe1 + (j << 8));
            const float4* h4 = (const float4*)h0;
            #pragma unroll 4
            for (int k = 0; k < 64; ++k) acc += dot4(wi[k], h4[k]);
            const float4* wh = (const float4*)(whhe + 262144 + (j << 8));
            const float4* h14 = (const float4*)hc1;
            #pragma unroll 4
            for (int k = 0; k < 64; ++k) acc += dot4(wh[k], h14[k]);
            gates[j] = acc;
        }
        __syncthreads();
        if (tid < 256) {
            float cn = sigf(gates[256 + tid]) * hc1[256 + tid] + sigf(gates[tid]) * tanhf_(gates[512 + tid]);
            float hn = sigf(gates[768 + tid]) * tanhf_(cn);
            hc1[256 + tid] = cn; hc1[tid] = hn;
            hexp[t * 256 + tid] = hn;
        }
        __syncthreads();
    }

    sm[tid] = 0.0f;
    float Pdreg[16], w2dr[16];
    #pragma unroll
    for (int jj = 0; jj < 16; ++jj) {
        int j = q16 + 16 * jj;
        w2dr[jj] = dw2[j];
        float acc = db1[j];
        const float4* w4 = (const float4*)(dw1 + j * 768 + 512);
        const float4* x4 = (const float4*)(hexp + g16 * 256);
        #pragma unroll 4
        for (int k = 0; k < 64; ++k) acc += dot4(w4[k], x4[k]);
        Pdreg[jj] = acc;
    }
    __syncthreads();

    const int j4 = tid >> 2;
    const int q4 = tid & 3;
    for (int t = 0; t < 64; ++t) {
        {
            const float4* w4 = (const float4*)(dw1 + j4 * 768 + q4 * 128);
            const float4* x4 = (const float4*)(hc1 + q4 * 128);
            float acc = 0.f;
            #pragma unroll 4
            for (int i = 0; i < 32; ++i) acc += dot4(w4[i], x4[i]);
            acc += __shfl_xor(acc, 1);
            acc += __shfl_xor(acc, 2);
            if (q4 == 0) hctS[j4] = acc;
        }
        __syncthreads();
        {
            float s = 0.f;
            #pragma unroll
            for (int jj = 0; jj < 16; ++jj)
                s += tanhf_(Pdreg[jj] + hctS[q16 + 16 * jj]) * w2dr[jj];
            s = red16(s);
            if (q16 == 0) scoreS[g16] = s;
        }
        __syncthreads();
        if (tid < 64) {
            float v = scoreS[tid], m = v;
            #pragma unroll
            for (int d = 1; d < 64; d <<= 1) m = fmaxf(m, __shfl_xor(m, d));
            float ex = __expf(v - m), s = ex;
            #pragma unroll
            for (int d = 1; d < 64; d <<= 1) s += __shfl_xor(s, d);
            aS[tid] = ex / s;
            if (tid == 0) full[256] = decin[t];
        }
        __syncthreads();
        {
            float acc = 0.f;
            #pragma unroll 4
            for (int i = 0; i < 16; ++i) {
                int tt = q4 + 4 * i;
                acc += hexp[tt * 256 + j4] * aS[tt];
            }
            acc += __shfl_xor(acc, 1);
            acc += __shfl_xor(acc, 2);
            if (q4 == 0) full[j4] = acc;
        }
        __syncthreads();
        {
            int j = tid;
            float acc = bihd[j] + bhhd[j];
            const float* wi = wihd0 + j * 257;
            #pragma unroll 8
            for (int k = 0; k < 257; ++k) acc += wi[k] * full[k];
            const float4* wh = (const float4*)(whhd + (j << 8));
            const float4* h4 = (const float4*)h0;
            #pragma unroll 4
            for (int k = 0; k < 64; ++k) acc += dot4(wh[k], h4[k]);
            gates[j] = acc;
        }
        __syncthreads();
        if (tid < 256) {
            float cn = sigf(gates[256 + tid]) * c0[tid] + sigf(gates[tid]) * tanhf_(gates[512 + tid]);
            float hn = sigf(gates[768 + tid]) * tanhf_(cn);
            c0[tid] = cn; h0[tid] = hn;
        }
        __syncthreads();
        {
            int j = tid;
            float acc = bihd[1024 + j] + bhhd[1024 + j];
            const float4* wi = (const float4*)(wihd1 + (j << 8));
            const float4* h4 = (const float4*)h0;
            #pragma unroll 4
            for (int k = 0; k < 64; ++k) acc += dot4(wi[k], h4[k]);
            const float4* wh = (const float4*)(whhd + 262144 + (j << 8));
            const float4* h14 = (const float4*)hc1;
            #pragma unroll 4
            for (int k = 0; k < 64; ++k) acc += dot4(wh[k], h14[k]);
            gates[j] = acc;
        }
        __syncthreads();
        if (tid < 256) {
            float cn = sigf(gates[256 + tid]) * hc1[256 + tid] + sigf(gates[tid]) * tanhf_(gates[512 + tid]);
            float hn = sigf(gates[768 + tid]) * tanhf_(cn);
            hc1[256 + tid] = cn; hc1[tid] = hn;
        }
        __syncthreads();
    }

    if (tid < 64) {
        float acc = 0.f;
        #pragma unroll
        for (int i = 0; i < 8; ++i) {
            int k = tid + 64 * i;
            float v = (k < 256) ? hc1[k] : full[k - 256];
            acc += v * pw[k];
        }
        acc = red64(acc);
        if (tid == 0) out[b] = fabsf(acc + pb[0]);
    }
}

extern "C" void kernel_launch(void* const* d_in, const int* in_sizes, int n_in,
                              void* d_out, int out_size, void* d_ws, size_t ws_size,
                              hipStream_t stream) {
    const float* inp   = (const float*)d_in[0];
    const float* wihe0 = (const float*)d_in[1];
    const float* wihe1 = (const float*)d_in[2];
    const float* whhe  = (const float*)d_in[3];
    const float* bihe  = (const float*)d_in[4];
    const float* bhhe  = (const float*)d_in[5];
    const float* wihd0 = (const float*)d_in[6];
    const float* wihd1 = (const float*)d_in[7];
    const float* whhd  = (const float*)d_in[8];
    const float* bihd  = (const float*)d_in[9];
    const float* bhhd  = (const float*)d_in[10];
    const float* aw1   = (const float*)d_in[11];
    const float* ab1   = (const float*)d_in[12];
    const float* aw2   = (const float*)d_in[13];
    const float* dw1   = (const float*)d_in[14];
    const float* db1   = (const float*)d_in[15];
    const float* dw2   = (const float*)d_in[16];
    const float* pw    = (const float*)d_in[17];
    const float* pb    = (const float*)d_in[18];
    float* out = (float*)d_out;

    if (ws_size >= (size_t)TOT_H * sizeof(__half)) {
        __half* wsh = (__half*)d_ws;
        repack16b<<<(TOT_H + 255) / 256, 256, 0, stream>>>(
            wihe0, wihe1, whhe, wihd0, wihd1, whhd, aw1, dw1, wsh);
        const int smem = L_TOT * 4;   // ~113 KB
        hipFuncSetAttribute((const void*)attn_lstm_v5,
                            hipFuncAttributeMaxDynamicSharedMemorySize, smem);
        attn_lstm_v5<<<64, NT, smem, stream>>>(
            inp, wsh, bihe, bhhe, bihd, bhhd,
            aw1, ab1, aw2, dw1, db1, dw2, pw, pb, out);
        return;
    }

    // fallback: fp32 v1 (no workspace needed)
    const int smem_bytes = 23492 * sizeof(float);
    hipFuncSetAttribute((const void*)attn_lstm,
                        hipFuncAttributeMaxDynamicSharedMemorySize, smem_bytes);
    attn_lstm<<<64, NT, smem_bytes, stream>>>(
        inp, wihe0, wihe1, whhe, bihe, bhhe,
        wihd0, wihd1, whhd, bihd, bhhd,
        aw1, ab1, aw2, dw1, db1, dw2, pw, pb, out);
}

// Round 6
// 2252.570 us; speedup vs baseline: 9.8817x; 1.8881x over previous
//
#include <hip/hip_runtime.h>
#include <hip/hip_fp16.h>
#include <math.h>

#define NT 1024

typedef _Float16 h2v __attribute__((ext_vector_type(2)));
union H8 { uint4 u; h2v h[4]; };

__device__ __forceinline__ float sigf(float x)   { return 1.0f / (1.0f + __expf(-x)); }
__device__ __forceinline__ float tanhf_(float x) { return 1.0f - 2.0f / (1.0f + __expf(2.0f * x)); }
__device__ __forceinline__ float dot4(float4 a, float4 b) {
    return a.x * b.x + a.y * b.y + a.z * b.z + a.w * b.w;
}
__device__ __forceinline__ float red16(float v) {
    v += __shfl_xor(v, 1); v += __shfl_xor(v, 2);
    v += __shfl_xor(v, 4); v += __shfl_xor(v, 8);
    return v;
}
__device__ __forceinline__ float red64(float v) {
    v += __shfl_xor(v, 1);  v += __shfl_xor(v, 2);  v += __shfl_xor(v, 4);
    v += __shfl_xor(v, 8);  v += __shfl_xor(v, 16); v += __shfl_xor(v, 32);
    return v;
}
__device__ __forceinline__ float dot2h(h2v a, h2v b, float c) {
#if __has_builtin(__builtin_amdgcn_fdot2)
    return __builtin_amdgcn_fdot2(a, b, c, false);
#else
    return c + (float)a[0] * (float)b[0] + (float)a[1] * (float)b[1];
#endif
}

// LLC-coherent read (bypasses L1/L2; no cache flush). Proven cross-XCD by the
// v3 counter spin (relaxed agent load observed remote atomicAdd results).
__device__ __forceinline__ float exr(const float* p) {
    return __hip_atomic_load(p, __ATOMIC_RELAXED, __HIP_MEMORY_SCOPE_AGENT);
}

// Fence-free 4-block group barrier. Writers must have issued their data
// atomics (atomicExch -> executes at LLC) before calling; the vmcnt(0) wait
// guarantees they are complete at the coherence point before the signal.
__device__ __forceinline__ void xbar(unsigned* ctr, unsigned target) {
    asm volatile("s_waitcnt vmcnt(0)" ::: "memory");
    __syncthreads();
    if (threadIdx.x == 0) {
        __hip_atomic_fetch_add(ctr, 1u, __ATOMIC_RELAXED, __HIP_MEMORY_SCOPE_AGENT);
        while (__hip_atomic_load(ctr, __ATOMIC_RELAXED, __HIP_MEMORY_SCOPE_AGENT) < target)
            __builtin_amdgcn_s_sleep(1);
    }
    __syncthreads();
}

// ws half-offsets (permuted-packed fp16 weights)
#define OFF_RA   0          // aw1[:, 0:512]          64 x 512
#define OFF_RE0  32768      // [wihe0|whhe0|pad]      1024 x 384
#define OFF_RE1  425984     // [wihe1|whhe1]          1024 x 512
#define OFF_RDW1 950272     // dw1[:, 0:512]          256 x 512
#define OFF_RD0  1081344    // [wihd0[:,0:256]|whhd0] 1024 x 512
#define OFF_RDT  1605632    // wihd0[:, 256]          1024
#define OFF_RD1  1606656    // [wihd1|whhd1]          1024 x 512
#define TOT_H    2130944

// K=512 GEMV: 16 lanes/row, 4 rows/wave-iter; jBase = global row base (weights,
// bias, rdt), ljBase = local output base.
template<int ITERS, bool BIAS, bool DT>
__device__ __forceinline__ void gemv512x(const __half* __restrict__ W,
                                         const __half* __restrict__ act,
                                         const float* __restrict__ bias,
                                         const __half* __restrict__ rdt, float dts,
                                         float* __restrict__ outg,
                                         int jBase, int ljBase) {
    const int lane = threadIdx.x & 63;
    const int q = lane & 15, g = lane >> 4;
    H8 a0, a1, a2, a3;
    a0.u = *(const uint4*)(act + 8 * q);
    a1.u = *(const uint4*)(act + 8 * q + 128);
    a2.u = *(const uint4*)(act + 8 * q + 256);
    a3.u = *(const uint4*)(act + 8 * q + 384);
    #pragma unroll 2
    for (int it = 0; it < ITERS; ++it) {
        const int j = jBase + it * 4 + g;
        const uint4* wp = (const uint4*)(W + ((size_t)j << 9) + 32 * q);
        H8 w0, w1, w2, w3;
        w0.u = wp[0]; w1.u = wp[1]; w2.u = wp[2]; w3.u = wp[3];
        float s0 = 0.f, s1 = 0.f;
        #pragma unroll
        for (int i = 0; i < 4; ++i) {
            s0 = dot2h(w0.h[i], a0.h[i], s0);
            s1 = dot2h(w1.h[i], a1.h[i], s1);
            s0 = dot2h(w2.h[i], a2.h[i], s0);
            s1 = dot2h(w3.h[i], a3.h[i], s1);
        }
        float s = s0 + s1;
        s += __shfl_xor(s, 1); s += __shfl_xor(s, 2);
        s += __shfl_xor(s, 4); s += __shfl_xor(s, 8);
        if (q == 0) {
            if (DT) s += dts * (float)rdt[j];
            outg[ljBase + it * 4 + g] = BIAS ? s + bias[j] : s;
        }
    }
}

// K=384 GEMV
template<int ITERS>
__device__ __forceinline__ void gemv384x(const __half* __restrict__ W,
                                         const __half* __restrict__ act,
                                         const float* __restrict__ bias,
                                         float* __restrict__ outg,
                                         int jBase, int ljBase) {
    const int lane = threadIdx.x & 63;
    const int q = lane & 15, g = lane >> 4;
    H8 a0, a1, a2;
    a0.u = *(const uint4*)(act + 8 * q);
    a1.u = *(const uint4*)(act + 8 * q + 128);
    a2.u = *(const uint4*)(act + 8 * q + 256);
    #pragma unroll 2
    for (int it = 0; it < ITERS; ++it) {
        const int j = jBase + it * 4 + g;
        const uint4* wp = (const uint4*)(W + (size_t)j * 384 + 24 * q);
        H8 w0, w1, w2;
        w0.u = wp[0]; w1.u = wp[1]; w2.u = wp[2];
        float s0 = 0.f, s1 = 0.f;
        #pragma unroll
        for (int i = 0; i < 4; ++i) {
            s0 = dot2h(w0.h[i], a0.h[i], s0);
            s1 = dot2h(w1.h[i], a1.h[i], s1);
            s0 = dot2h(w2.h[i], a2.h[i], s0);
        }
        float s = s0 + s1;
        s += __shfl_xor(s, 1); s += __shfl_xor(s, 2);
        s += __shfl_xor(s, 4); s += __shfl_xor(s, 8);
        if (q == 0) outg[ljBase + it * 4 + g] = s + bias[j];
    }
}

// ---------------- v6 LDS layout (floats) ----------------
#define M_HEXP  0        // 16384
#define M_XET   16384    // 4352 (64 x 68)
#define M_GSL   20736    // 256  (local gate slice)
#define M_HCT   20992    // 256
#define M_TMP   21248    // 64
#define M_SCORE 21312    // 64
#define M_AS    21376    // 64
#define M_C0    21440    // 64  (private c0 slice)
#define M_C1    21504    // 64  (private c1 slice)
#define M_HC1F  21568    // 256
#define M_DECIN 21824    // 64
#define M_PARTF 21888    // 256
#define M_BE0   22144    // 1024
#define M_BE1   23168    // 1024
#define M_BD0   24192    // 1024
#define M_BD1   25216    // 1024
#define M_AHC   26240    // 256 f = 512 halfs [h1|c1]
#define M_AE0   26496    // 192 f = 384 halfs [x_in|h0|0]
#define M_AHH   26688    // 256 f = 512 halfs [h0|h1]
#define M_AD0   26944    // 256 f = 512 halfs [partial|h0]
#define M_RDT   27200    // 512 f = 1024 halfs
#define M_TOT   27712

// ============ v6: 4 blocks per batch element, fence-free LLC exchange ======
extern "C" __global__ void __launch_bounds__(NT)
attn_lstm_v6(const float* __restrict__ inp,  const __half* __restrict__ wsh,
             float* __restrict__ h0x, float* __restrict__ h1x,
             float* __restrict__ hcx, unsigned* __restrict__ barc,
             const float* __restrict__ bihe, const float* __restrict__ bhhe,
             const float* __restrict__ bihd, const float* __restrict__ bhhd,
             const float* __restrict__ aw1,  const float* __restrict__ ab1,
             const float* __restrict__ aw2,
             const float* __restrict__ dw1,  const float* __restrict__ db1,
             const float* __restrict__ dw2,
             const float* __restrict__ pw,   const float* __restrict__ pb,
             float* __restrict__ out)
{
    extern __shared__ __align__(16) float sm[];
    float* hexp   = sm + M_HEXP;
    float* xeT    = sm + M_XET;
    float* gsl    = sm + M_GSL;
    float* hctL   = sm + M_HCT;
    float* tmp64  = sm + M_TMP;
    float* scoreS = sm + M_SCORE;
    float* aS     = sm + M_AS;
    float* c0L    = sm + M_C0;
    float* c1L    = sm + M_C1;
    float* hc1f   = sm + M_HC1F;
    float* decin  = sm + M_DECIN;
    float* partF  = sm + M_PARTF;
    float* bE0    = sm + M_BE0;
    float* bE1    = sm + M_BE1;
    float* bD0    = sm + M_BD0;
    float* bD1    = sm + M_BD1;
    __half* aHC   = (__half*)(sm + M_AHC);
    __half* aE0   = (__half*)(sm + M_AE0);
    __half* aHH   = (__half*)(sm + M_AHH);
    __half* aD0   = (__half*)(sm + M_AD0);
    __half* rdtL  = (__half*)(sm + M_RDT);

    const __half* RA   = wsh + OFF_RA;
    const __half* RE0  = wsh + OFF_RE0;
    const __half* RE1  = wsh + OFF_RE1;
    const __half* RDW1 = wsh + OFF_RDW1;
    const __half* RD0  = wsh + OFF_RD0;
    const __half* RD1  = wsh + OFF_RD1;

    const int tid = threadIdx.x;
    const int b   = blockIdx.x >> 2;
    const int co  = blockIdx.x & 3;
    const int w   = tid >> 6;
    unsigned* ctr = barc + (b << 4);
    unsigned  ph  = 0;

    // ---- init ----
    if (tid < 64) { c0L[tid] = 0.f; c1L[tid] = 0.f; }
    for (int i = tid; i < 960; i += NT) sm[M_AHC + i] = 0.0f;   // aHC..aD0
    if (tid < 512) sm[M_RDT + tid] = ((const float*)(wsh + OFF_RDT))[tid];
    {
        int j = tid;
        bE0[j] = bihe[j]        + bhhe[j];
        bE1[j] = bihe[1024 + j] + bhhe[1024 + j];
        bD0[j] = bihd[j]        + bhhd[j];
        bD1[j] = bihd[1024 + j] + bhhd[1024 + j];
    }
    const float* ib = inp + b * (64 * 65);
    for (int i = tid; i < 4096; i += NT) {
        int t = i & 63, e = i >> 6;
        xeT[e * 68 + t] = ib[t * 65 + 1 + e];
    }
    if (tid < 64) decin[tid] = ib[tid * 65];
    __syncthreads();

    const int g16 = tid >> 4, q16 = tid & 15;
    // split-gemv row mapping: wave w -> gate gg, column block cb
    const int gg = w >> 2, cb = (w & 3) << 4;
    const int jB  = gg * 256 + co * 64 + cb;   // global weight row base
    const int ljB = gg * 64 + cb;              // local gate-slice base

    // ---- encoder attention P (input part + bias, fp32 one-time) -> regs ----
    float Preg[4], w2r[4];
    #pragma unroll
    for (int jj = 0; jj < 4; ++jj) {
        int j = q16 + 16 * jj;
        w2r[jj] = aw2[j];
        float acc = ab1[j];
        const float4* w4 = (const float4*)(aw1 + j * 576 + 512);
        const float4* x4 = (const float4*)(xeT + g16 * 68);
        #pragma unroll 4
        for (int k = 0; k < 16; ++k) acc += dot4(w4[k], x4[k]);
        Preg[jj] = acc;
    }

    // ================= encoder: 64 steps, 2 exchanges each =================
    for (int t = 0; t < 64; ++t) {
        const int p = t & 1;
        float* h0b = h0x + p * 16384 + b * 256;
        float* h1b = h1x + p * 32768 + b * 512;
        // E1 (replicated): hct[j<64] = [h1;c1] . aw1[j,0:512)
        gemv512x<1, false, false>(RA, aHC, nullptr, nullptr, 0.f, hctL, w * 4, w * 4);
        __syncthreads();
        // E2: score[e]
        {
            float s = 0.f;
            #pragma unroll
            for (int jj = 0; jj < 4; ++jj)
                s += tanhf_(Preg[jj] + hctL[q16 + 16 * jj]) * w2r[jj];
            s = red16(s);
            if (q16 == 0) scoreS[g16] = s;
        }
        __syncthreads();
        // E3: softmax + x_in
        if (tid < 64) {
            float v = scoreS[tid], m = v;
            #pragma unroll
            for (int d = 1; d < 64; d <<= 1) m = fmaxf(m, __shfl_xor(m, d));
            float ex = __expf(v - m), s = ex;
            #pragma unroll
            for (int d = 1; d < 64; d <<= 1) s += __shfl_xor(s, d);
            aE0[tid] = __float2half((ex / s) * xeT[tid * 68 + t]);
        }
        __syncthreads();
        // E4 (split): layer0 gates, own 256 rows
        gemv384x<4>(RE0, aE0, bE0, gsl, jB, ljB);
        __syncthreads();
        // E5: elementwise l0 (own 64 channels) -> exchange h0
        if (tid < 64) {
            float cn = sigf(gsl[64 + tid]) * c0L[tid] + sigf(gsl[tid]) * tanhf_(gsl[128 + tid]);
            float hn = sigf(gsl[192 + tid]) * tanhf_(cn);
            c0L[tid] = cn;
            atomicExch(&h0b[co * 64 + tid], hn);
        }
        xbar(ctr, ++ph * 4u);
        if (tid < 256) {
            __half hh = __float2half(exr(&h0b[tid]));
            aE0[64 + tid] = hh; aHH[tid] = hh;
        }
        __syncthreads();
        // E6 (split): layer1 gates
        gemv512x<4, true, false>(RE1, aHH, bE1, nullptr, 0.f, gsl, jB, ljB);
        __syncthreads();
        // E7: elementwise l1 -> exchange h1,c1
        if (tid < 64) {
            float cn = sigf(gsl[64 + tid]) * c1L[tid] + sigf(gsl[tid]) * tanhf_(gsl[128 + tid]);
            float hn = sigf(gsl[192 + tid]) * tanhf_(cn);
            c1L[tid] = cn;
            atomicExch(&h1b[co * 64 + tid], hn);
            atomicExch(&h1b[256 + co * 64 + tid], cn);
        }
        xbar(ctr, ++ph * 4u);
        if (tid < 512) {
            float v = exr(&h1b[tid]);
            __half hh = __float2half(v);
            aHC[tid] = hh;
            if (tid < 256) { aHH[256 + tid] = hh; hexp[t * 256 + tid] = v; }
        }
        __syncthreads();
    }

    // ---- transition: zero recurrent state; Pd precompute -> regs ----
    if (tid < 64) { c0L[tid] = 0.f; c1L[tid] = 0.f; }
    for (int i = tid; i < 960; i += NT) sm[M_AHC + i] = 0.0f;
    __syncthreads();
    float Pdreg[16], w2dr[16];
    #pragma unroll
    for (int jj = 0; jj < 16; ++jj) {
        int j = q16 + 16 * jj;
        w2dr[jj] = dw2[j];
        float acc = db1[j];
        const float4* w4 = (const float4*)(dw1 + j * 768 + 512);
        const float4* x4 = (const float4*)(hexp + g16 * 256);
        #pragma unroll 4
        for (int k = 0; k < 64; ++k) acc += dot4(w4[k], x4[k]);
        Pdreg[jj] = acc;
    }
    __syncthreads();

    // ================= decoder: 64 steps, 3 exchanges each =================
    const int j4 = tid >> 2, q4 = tid & 3;
    for (int t = 0; t < 64; ++t) {
        const int p = t & 1;
        float* h0b = h0x + p * 16384 + b * 256;
        float* h1b = h1x + p * 32768 + b * 512;
        float* hcb = hcx + p * 16384 + b * 256;
        // D1 (split): hctd rows co*64..co*64+64
        gemv512x<1, false, false>(RDW1, aHC, nullptr, nullptr, 0.f, tmp64,
                                  co * 64 + w * 4, w * 4);
        __syncthreads();
        if (tid < 64) atomicExch(&hcb[co * 64 + tid], tmp64[tid]);
        xbar(ctr, ++ph * 4u);
        if (tid < 256) hctL[tid] = exr(&hcb[tid]);
        __syncthreads();
        // D2: score[t']
        {
            float s = 0.f;
            #pragma unroll
            for (int jj = 0; jj < 16; ++jj)
                s += tanhf_(Pdreg[jj] + hctL[q16 + 16 * jj]) * w2dr[jj];
            s = red16(s);
            if (q16 == 0) scoreS[g16] = s;
        }
        __syncthreads();
        // D3: softmax -> aS
        if (tid < 64) {
            float v = scoreS[tid], m = v;
            #pragma unroll
            for (int d = 1; d < 64; d <<= 1) m = fmaxf(m, __shfl_xor(m, d));
            float ex = __expf(v - m), s = ex;
            #pragma unroll
            for (int d = 1; d < 64; d <<= 1) s += __shfl_xor(s, d);
            aS[tid] = ex / s;
        }
        __syncthreads();
        // D4 (replicated): partial[c]
        {
            float acc = 0.f;
            #pragma unroll 4
            for (int i = 0; i < 16; ++i) {
                int tt = q4 + 4 * i;
                acc += hexp[tt * 256 + j4] * aS[tt];
            }
            acc += __shfl_xor(acc, 1);
            acc += __shfl_xor(acc, 2);
            if (q4 == 0) { aD0[j4] = __float2half(acc); partF[j4] = acc; }
        }
        __syncthreads();
        // D5 (split): layer0 gates (+ d_t column)
        gemv512x<4, true, true>(RD0, aD0, bD0, rdtL, decin[t], gsl, jB, ljB);
        __syncthreads();
        // D6: elementwise l0 -> exchange h0
        if (tid < 64) {
            float cn = sigf(gsl[64 + tid]) * c0L[tid] + sigf(gsl[tid]) * tanhf_(gsl[128 + tid]);
            float hn = sigf(gsl[192 + tid]) * tanhf_(cn);
            c0L[tid] = cn;
            atomicExch(&h0b[co * 64 + tid], hn);
        }
        xbar(ctr, ++ph * 4u);
        if (tid < 256) {
            __half hh = __float2half(exr(&h0b[tid]));
            aD0[256 + tid] = hh; aHH[tid] = hh;
        }
        __syncthreads();
        // D7 (split): layer1 gates
        gemv512x<4, true, false>(RD1, aHH, bD1, nullptr, 0.f, gsl, jB, ljB);
        __syncthreads();
        // D8: elementwise l1 -> exchange h1,c1
        if (tid < 64) {
            float cn = sigf(gsl[64 + tid]) * c1L[tid] + sigf(gsl[tid]) * tanhf_(gsl[128 + tid]);
            float hn = sigf(gsl[192 + tid]) * tanhf_(cn);
            c1L[tid] = cn;
            atomicExch(&h1b[co * 64 + tid], hn);
            atomicExch(&h1b[256 + co * 64 + tid], cn);
        }
        xbar(ctr, ++ph * 4u);
        if (tid < 512) {
            float v = exr(&h1b[tid]);
            __half hh = __float2half(v);
            aHC[tid] = hh;
            if (tid < 256) { aHH[256 + tid] = hh; hc1f[tid] = v; }
        }
        __syncthreads();
    }

    // ---- output (one block per b) ----
    if (co == 0 && tid < 64) {
        float acc = 0.f;
        #pragma unroll
        for (int i = 0; i < 8; ++i) {
            int k = tid + 64 * i;
            float v = (k < 256) ? hc1f[k] : partF[k - 256];
            acc += v * pw[k];
        }
        acc = red64(acc);
        if (tid == 0) out[b] = fabsf(acc + pb[0]);
    }
}

// ---------------- v5 LDS layout (fallback kernel) ----------------
#define L_HEXP   0
#define L_XET    16384
#define L_GSL    20736
#define L_HCT    21760
#define L_SCORE  22016
#define L_AS     22080
#define L_C0     22144
#define L_HC1F   22400
#define L_DECIN  22912
#define L_PARTF  22976
#define L_BE0    23232
#define L_BE1    24256
#define L_BD0    25280
#define L_BD1    26304
#define L_AHC    27328
#define L_AE0    27584
#define L_AHH    27776
#define L_AD0    28032
#define L_RDT    28288
#define L_TOT    28800

extern "C" __global__ void __launch_bounds__(NT)
attn_lstm_v5(const float* __restrict__ inp,  const __half* __restrict__ wsh,
             const float* __restrict__ bihe, const float* __restrict__ bhhe,
             const float* __restrict__ bihd, const float* __restrict__ bhhd,
             const float* __restrict__ aw1,  const float* __restrict__ ab1,
             const float* __restrict__ aw2,
             const float* __restrict__ dw1,  const float* __restrict__ db1,
             const float* __restrict__ dw2,
             const float* __restrict__ pw,   const float* __restrict__ pb,
             float* __restrict__ out)
{
    extern __shared__ __align__(16) float sm[];
    float* hexp   = sm + L_HEXP;
    float* xeT    = sm + L_XET;
    float* gsl    = sm + L_GSL;
    float* hctL   = sm + L_HCT;
    float* scoreS = sm + L_SCORE;
    float* aS     = sm + L_AS;
    float* c0L    = sm + L_C0;
    float* hc1f   = sm + L_HC1F;
    float* decin  = sm + L_DECIN;
    float* partF  = sm + L_PARTF;
    float* bE0    = sm + L_BE0;
    float* bE1    = sm + L_BE1;
    float* bD0    = sm + L_BD0;
    float* bD1    = sm + L_BD1;
    __half* aHC   = (__half*)(sm + L_AHC);
    __half* aE0   = (__half*)(sm + L_AE0);
    __half* aHH   = (__half*)(sm + L_AHH);
    __half* aD0   = (__half*)(sm + L_AD0);
    __half* rdtL  = (__half*)(sm + L_RDT);

    const __half* RA   = wsh + OFF_RA;
    const __half* RE0  = wsh + OFF_RE0;
    const __half* RE1  = wsh + OFF_RE1;
    const __half* RDW1 = wsh + OFF_RDW1;
    const __half* RD0  = wsh + OFF_RD0;
    const __half* RD1  = wsh + OFF_RD1;

    const int b   = blockIdx.x;
    const int tid = threadIdx.x;
    const int w   = tid >> 6;

    for (int i = tid; i < (L_BE0 - L_C0); i += NT) sm[L_C0 + i] = 0.0f;
    for (int i = tid; i < (L_RDT - L_AHC); i += NT) sm[L_AHC + i] = 0.0f;
    if (tid < 512) sm[L_RDT + tid] = ((const float*)(wsh + OFF_RDT))[tid];
    {
        int j = tid;
        bE0[j] = bihe[j]        + bhhe[j];
        bE1[j] = bihe[1024 + j] + bhhe[1024 + j];
        bD0[j] = bihd[j]        + bhhd[j];
        bD1[j] = bihd[1024 + j] + bhhd[1024 + j];
    }
    const float* ib = inp + b * (64 * 65);
    for (int i = tid; i < 4096; i += NT) {
        int t = i & 63, e = i >> 6;
        xeT[e * 68 + t] = ib[t * 65 + 1 + e];
    }
    if (tid < 64) decin[tid] = ib[tid * 65];
    __syncthreads();

    const int g16 = tid >> 4, q16 = tid & 15;

    float Preg[4], w2r[4];
    #pragma unroll
    for (int jj = 0; jj < 4; ++jj) {
        int j = q16 + 16 * jj;
        w2r[jj] = aw2[j];
        float acc = ab1[j];
        const float4* w4 = (const float4*)(aw1 + j * 576 + 512);
        const float4* x4 = (const float4*)(xeT + g16 * 68);
        #pragma unroll 4
        for (int k = 0; k < 16; ++k) acc += dot4(w4[k], x4[k]);
        Preg[jj] = acc;
    }

    for (int t = 0; t < 64; ++t) {
        gemv512x<1, false, false>(RA, aHC, nullptr, nullptr, 0.f, hctL, w * 4, w * 4);
        __syncthreads();
        {
            float s = 0.f;
            #pragma unroll
            for (int jj = 0; jj < 4; ++jj)
                s += tanhf_(Preg[jj] + hctL[q16 + 16 * jj]) * w2r[jj];
            s = red16(s);
            if (q16 == 0) scoreS[g16] = s;
        }
        __syncthreads();
        if (tid < 64) {
            float v = scoreS[tid], m = v;
            #pragma unroll
            for (int d = 1; d < 64; d <<= 1) m = fmaxf(m, __shfl_xor(m, d));
            float ex = __expf(v - m), s = ex;
            #pragma unroll
            for (int d = 1; d < 64; d <<= 1) s += __shfl_xor(s, d);
            aE0[tid] = __float2half((ex / s) * xeT[tid * 68 + t]);
        }
        __syncthreads();
        gemv384x<16>(RE0, aE0, bE0, gsl, w * 64, w * 64);
        __syncthreads();
        if (tid < 256) {
            float cn = sigf(gsl[256 + tid]) * c0L[tid] + sigf(gsl[tid]) * tanhf_(gsl[512 + tid]);
            float hn = sigf(gsl[768 + tid]) * tanhf_(cn);
            c0L[tid] = cn;
            __half hh = __float2half(hn);
            aE0[64 + tid] = hh; aHH[tid] = hh;
        }
        __syncthreads();
        gemv512x<16, true, false>(RE1, aHH, bE1, nullptr, 0.f, gsl, w * 64, w * 64);
        __syncthreads();
        if (tid < 256) {
            float cp = hc1f[256 + tid];
            float cn = sigf(gsl[256 + tid]) * cp + sigf(gsl[tid]) * tanhf_(gsl[512 + tid]);
            float hn = sigf(gsl[768 + tid]) * tanhf_(cn);
            hc1f[tid] = hn; hc1f[256 + tid] = cn;
            __half hh = __float2half(hn);
            aHC[tid] = hh; aHC[256 + tid] = __float2half(cn);
            aHH[256 + tid] = hh;
            hexp[t * 256 + tid] = hn;
        }
        __syncthreads();
    }

    if (tid < 256) { c0L[tid] = 0.0f; hc1f[tid] = 0.0f; hc1f[256 + tid] = 0.0f; }
    for (int i = tid; i < (L_RDT - L_AHC); i += NT) sm[L_AHC + i] = 0.0f;
    __syncthreads();
    float Pdreg[16], w2dr[16];
    #pragma unroll
    for (int jj = 0; jj < 16; ++jj) {
        int j = q16 + 16 * jj;
        w2dr[jj] = dw2[j];
        float acc = db1[j];
        const float4* w4 = (const float4*)(dw1 + j * 768 + 512);
        const float4* x4 = (const float4*)(hexp + g16 * 256);
        #pragma unroll 4
        for (int k = 0; k < 64; ++k) acc += dot4(w4[k], x4[k]);
        Pdreg[jj] = acc;
    }
    __syncthreads();

    const int j4 = tid >> 2, q4 = tid & 3;
    for (int t = 0; t < 64; ++t) {
        gemv512x<4, false, false>(RDW1, aHC, nullptr, nullptr, 0.f, hctL, w * 16, w * 16);
        __syncthreads();
        {
            float s = 0.f;
            #pragma unroll
            for (int jj = 0; jj < 16; ++jj)
                s += tanhf_(Pdreg[jj] + hctL[q16 + 16 * jj]) * w2dr[jj];
            s = red16(s);
            if (q16 == 0) scoreS[g16] = s;
        }
        __syncthreads();
        if (tid < 64) {
            float v = scoreS[tid], m = v;
            #pragma unroll
            for (int d = 1; d < 64; d <<= 1) m = fmaxf(m, __shfl_xor(m, d));
            float ex = __expf(v - m), s = ex;
            #pragma unroll
            for (int d = 1; d < 64; d <<= 1) s += __shfl_xor(s, d);
            aS[tid] = ex / s;
        }
        __syncthreads();
        {
            float acc = 0.f;
            #pragma unroll 4
            for (int i = 0; i < 16; ++i) {
                int tt = q4 + 4 * i;
                acc += hexp[tt * 256 + j4] * aS[tt];
            }
            acc += __shfl_xor(acc, 1);
            acc += __shfl_xor(acc, 2);
            if (q4 == 0) { aD0[j4] = __float2half(acc); partF[j4] = acc; }
        }
        __syncthreads();
        gemv512x<16, true, true>(RD0, aD0, bD0, rdtL, decin[t], gsl, w * 64, w * 64);
        __syncthreads();
        if (tid < 256) {
            float cn = sigf(gsl[256 + tid]) * c0L[tid] + sigf(gsl[tid]) * tanhf_(gsl[512 + tid]);
            float hn = sigf(gsl[768 + tid]) * tanhf_(cn);
            c0L[tid] = cn;
            __half hh = __float2half(hn);
            aD0[256 + tid] = hh; aHH[tid] = hh;
        }
        __syncthreads();
        gemv512x<16, true, false>(RD1, aHH, bD1, nullptr, 0.f, gsl, w * 64, w * 64);
        __syncthreads();
        if (tid < 256) {
            float cp = hc1f[256 + tid];
            float cn = sigf(gsl[256 + tid]) * cp + sigf(gsl[tid]) * tanhf_(gsl[512 + tid]);
            float hn = sigf(gsl[768 + tid]) * tanhf_(cn);
            hc1f[tid] = hn; hc1f[256 + tid] = cn;
            __half hh = __float2half(hn);
            aHC[tid] = hh; aHC[256 + tid] = __float2half(cn);
            aHH[256 + tid] = hh;
        }
        __syncthreads();
    }

    if (tid < 64) {
        float acc = 0.f;
        #pragma unroll
        for (int i = 0; i < 8; ++i) {
            int k = tid + 64 * i;
            float v = (k < 256) ? hc1f[k] : partF[k - 256];
            acc += v * pw[k];
        }
        acc = red64(acc);
        if (tid == 0) out[b] = fabsf(acc + pb[0]);
    }
}

// ---- fp16 permuted repack (unchanged from R5) ----
extern "C" __global__ void repack16b(const float* __restrict__ wihe0,
                                     const float* __restrict__ wihe1,
                                     const float* __restrict__ whhe,
                                     const float* __restrict__ wihd0,
                                     const float* __restrict__ wihd1,
                                     const float* __restrict__ whhd,
                                     const float* __restrict__ aw1,
                                     const float* __restrict__ dw1,
                                     __half* __restrict__ ws) {
    int idx = blockIdx.x * blockDim.x + threadIdx.x;
    if (idx >= TOT_H) return;
    int o = idx; float v;
    if (o < 32768) {
        int j = o >> 9, p = o & 511;
        int q = p >> 5, r = p & 31, c = r >> 3, e = r & 7;
        int k = 8 * q + 128 * c + e;
        v = aw1[j * 576 + k];
        ws[OFF_RA + o] = __float2half_rn(v); return;
    }
    o -= 32768;
    if (o < 393216) {
        int j = o / 384, p = o - j * 384;
        int q = p / 24, r = p - q * 24, c = r >> 3, e = r & 7;
        int k = 8 * q + 128 * c + e;
        v = (k < 64) ? wihe0[j * 64 + k] : (k < 320 ? whhe[j * 256 + (k - 64)] : 0.0f);
        ws[OFF_RE0 + o] = __float2half_rn(v); return;
    }
    o -= 393216;
    if (o < 524288) {
        int j = o >> 9, p = o & 511;
        int q = p >> 5, r = p & 31, c = r >> 3, e = r & 7;
        int k = 8 * q + 128 * c + e;
        v = (k < 256) ? wihe1[j * 256 + k] : whhe[262144 + j * 256 + (k - 256)];
        ws[OFF_RE1 + o] = __float2half_rn(v); return;
    }
    o -= 524288;
    if (o < 131072) {
        int j = o >> 9, p = o & 511;
        int q = p >> 5, r = p & 31, c = r >> 3, e = r & 7;
        int k = 8 * q + 128 * c + e;
        v = dw1[j * 768 + k];
        ws[OFF_RDW1 + o] = __float2half_rn(v); return;
    }
    o -= 131072;
    if (o < 524288) {
        int j = o >> 9, p = o & 511;
        int q = p >> 5, r = p & 31, c = r >> 3, e = r & 7;
        int k = 8 * q + 128 * c + e;
        v = (k < 256) ? wihd0[j * 257 + k] : whhd[j * 256 + (k - 256)];
        ws[OFF_RD0 + o] = __float2half_rn(v); return;
    }
    o -= 524288;
    if (o < 1024) {
        v = wihd0[o * 257 + 256];
        ws[OFF_RDT + o] = __float2half_rn(v); return;
    }
    o -= 1024;
    {
        int j = o >> 9, p = o & 511;
        int q = p >> 5, r = p & 31, c = r >> 3, e = r & 7;
        int k = 8 * q + 128 * c + e;
        v = (k < 256) ? wihd1[j * 256 + k] : whhd[262144 + j * 256 + (k - 256)];
        ws[OFF_RD1 + o] = __float2half_rn(v);
    }
}

extern "C" void kernel_launch(void* const* d_in, const int* in_sizes, int n_in,
                              void* d_out, int out_size, void* d_ws, size_t ws_size,
                              hipStream_t stream) {
    const float* inp   = (const float*)d_in[0];
    const float* wihe0 = (const float*)d_in[1];
    const float* wihe1 = (const float*)d_in[2];
    const float* whhe  = (const float*)d_in[3];
    const float* bihe  = (const float*)d_in[4];
    const float* bhhe  = (const float*)d_in[5];
    const float* wihd0 = (const float*)d_in[6];
    const float* wihd1 = (const float*)d_in[7];
    const float* whhd  = (const float*)d_in[8];
    const float* bihd  = (const float*)d_in[9];
    const float* bhhd  = (const float*)d_in[10];
    const float* aw1   = (const float*)d_in[11];
    const float* ab1   = (const float*)d_in[12];
    const float* aw2   = (const float*)d_in[13];
    const float* dw1   = (const float*)d_in[14];
    const float* db1   = (const float*)d_in[15];
    const float* dw2   = (const float*)d_in[16];
    const float* pw    = (const float*)d_in[17];
    const float* pb    = (const float*)d_in[18];
    float* out = (float*)d_out;

    // ws layout (float offsets): fp16 weights occupy [0, TOT_H/2)
    const size_t EX0 = TOT_H / 2;            // 1,065,472
    const size_t H0X = EX0;                  // 2*64*256 = 32768
    const size_t H1X = EX0 + 32768;          // 2*64*512 = 65536
    const size_t HCX = EX0 + 98304;          // 2*64*256 = 32768
    const size_t CTR = EX0 + 131072;         // 64*16 uints
    const size_t NEED6 = (CTR + 1024) * sizeof(float);

    if (ws_size >= NEED6) {
        float* ws32 = (float*)d_ws;
        __half* wsh = (__half*)d_ws;
        hipMemsetAsync((char*)d_ws + CTR * sizeof(float), 0, 4096, stream);
        repack16b<<<(TOT_H + 255) / 256, 256, 0, stream>>>(
            wihe0, wihe1, whhe, wihd0, wihd1, whhd, aw1, dw1, wsh);
        const int smem = M_TOT * 4;   // ~108 KB
        hipFuncSetAttribute((const void*)attn_lstm_v6,
                            hipFuncAttributeMaxDynamicSharedMemorySize, smem);
        attn_lstm_v6<<<256, NT, smem, stream>>>(
            inp, wsh, ws32 + H0X, ws32 + H1X, ws32 + HCX,
            (unsigned*)(ws32 + CTR),
            bihe, bhhe, bihd, bhhd,
            aw1, ab1, aw2, dw1, db1, dw2, pw, pb, out);
        return;
    }

    // fallback: v5 single-block-per-batch
    if (ws_size >= (size_t)TOT_H * sizeof(__half)) {
        __half* wsh = (__half*)d_ws;
        repack16b<<<(TOT_H + 255) / 256, 256, 0, stream>>>(
            wihe0, wihe1, whhe, wihd0, wihd1, whhd, aw1, dw1, wsh);
        const int smem = L_TOT * 4;
        hipFuncSetAttribute((const void*)attn_lstm_v5,
                            hipFuncAttributeMaxDynamicSharedMemorySize, smem);
        attn_lstm_v5<<<64, NT, smem, stream>>>(
            inp, wsh, bihe, bhhe, bihd, bhhd,
            aw1, ab1, aw2, dw1, db1, dw2, pw, pb, out);
    }
}